// Round 2
// baseline (1087.452 us; speedup 1.0000x reference)
//
#include <hip/hip_runtime.h>
#include <hip/hip_bf16.h>
#include <math.h>

#define Bx   32
#define Nx   2048
#define Sx   256
#define NSx  16
#define CINx 256

typedef unsigned short u16;
typedef unsigned int   u32;

__device__ __forceinline__ float b2f(u16 u) {
  union { u32 i; float f; } v; v.i = ((u32)u) << 16; return v.f;
}
__device__ __forceinline__ u16 f2b(float x) {  // RNE f32->bf16
  u32 u = __float_as_uint(x);
  u32 r = (u + 0x7FFFu + ((u >> 16) & 1u)) >> 16;
  return (u16)r;
}
// dtype-adaptive input load: bf=1 -> buffer holds bf16, bf=0 -> f32
__device__ __forceinline__ float ldin(const void* p, int i, int bf) {
  return bf ? b2f(((const u16*)p)[i]) : ((const float*)p)[i];
}

// ---------------- workspace layout (bytes) ----------------
#define OFF_FEATT 0                      // bf16 (B,N,C)   33554432
#define OFF_XT    (33554432)             // f32 (B,S,128)   4194304
#define OFF_T     (OFF_XT + 4194304)     // f32 (B,64,S)    2097152
#define OFF_YT    (OFF_T + 2097152)      // f32 (B,S,128)   4194304
#define OFF_NXYZ  (OFF_YT + 4194304)     // f32 (B,S,3)       98304
#define OFF_IDX   (OFF_NXYZ + 98304)     // i32 (B,S,16)     524288
#define OFF_ATT   (OFF_IDX + 524288)     // f32 (B,4)           512
#define OFF_W0R   (OFF_ATT + 512)        // f32 128x260      133120
#define OFF_B0    (OFF_W0R + 133120)
#define OFF_W1R   (OFF_B0 + 512)         // f32 128x128
#define OFF_B1    (OFF_W1R + 65536)
#define OFF_W2R   (OFF_B1 + 512)
#define OFF_B2    (OFF_W2R + 65536)
#define OFF_WTT   (OFF_B2 + 512)         // f32 128x64 (c-major)
#define OFF_WPT   (OFF_WTT + 32768)
#define OFF_WGT   (OFF_WPT + 32768)
#define OFF_C1T   (OFF_WGT + 32768)      // f32 128x128 (c-major, bn-folded)
#define OFF_D1    (OFF_C1T + 65536)
#define OFF_C2T   (OFF_D1 + 512)
#define OFF_D2    (OFF_C2T + 65536)
#define OFF_C3T   (OFF_D2 + 512)         // f32 128x43 (c-major)
#define OFF_XYZF  (OFF_C3T + 22016)      // f32 (B,N,3)      786432
#define OFF_WZF   (OFF_XYZF + 786432)    // f32 128x16         8192
#define OFF_GNG   (OFF_WZF + 8192)       // f32 128             512
#define OFF_GNB   (OFF_GNG + 512)
#define OFF_C3B   (OFF_GNB + 512)        // f32 43              512
#define OFF_FLAG  (OFF_C3B + 512)        // i32                 512

// ---------------- dtype sniff: decide bf16 vs f32 inputs from xyz bits ----------------
__global__ __launch_bounds__(256) void k_sniff(const u32* __restrict__ w, int* __restrict__ flag) {
  __shared__ int cnt;
  int t = threadIdx.x;
  if (t == 0) cnt = 0;
  __syncthreads();
  u32 x = w[t];
  int e_lo = (x >> 7) & 0xFF;                 // exponent field if low u16 were a bf16
  if (e_lo >= 100 && e_lo <= 140) atomicAdd(&cnt, 1);
  __syncthreads();
  if (t == 0) *flag = (cnt > 128) ? 1 : 0;    // 1 = inputs are bf16
}

// ---------------- xyz -> f32 staging ----------------
__global__ __launch_bounds__(256) void k_cvt(const void* __restrict__ xyz, float* __restrict__ xyzF,
                                             const int* __restrict__ flagp) {
  int bf = *flagp;
  int i = blockIdx.x * 256 + threadIdx.x;
  if (i < Bx * Nx * 3) xyzF[i] = ldin(xyz, i, bf);
}

// ---------------- prep: fold BN into weights, transpose layouts, convert to f32 ----------------
__global__ __launch_bounds__(256) void k_prep(
    const void* sa_w0, const void* sa_w1, const void* sa_w2,
    const void* sa_g,  const void* sa_b,  const void* sa_m, const void* sa_v,
    const void* wt, const void* wp, const void* wg, const void* wzI,
    const void* gngI, const void* gnbI,
    const void* c1w, const void* c1b,
    const void* bn1g, const void* bn1b, const void* bn1m, const void* bn1v,
    const void* c2w, const void* c2b,
    const void* bn2g, const void* bn2b, const void* bn2m, const void* bn2v,
    const void* c3w, const void* c3bI,
    float* __restrict__ w0R, float* __restrict__ b0, float* __restrict__ w1R, float* __restrict__ b1,
    float* __restrict__ w2R, float* __restrict__ b2,
    float* __restrict__ wtT, float* __restrict__ wpT, float* __restrict__ wgT,
    float* __restrict__ c1T, float* __restrict__ d1, float* __restrict__ c2T, float* __restrict__ d2,
    float* __restrict__ c3T, float* __restrict__ wzF, float* __restrict__ gngF,
    float* __restrict__ gnbF, float* __restrict__ c3bF,
    const int* __restrict__ flagp) {
  int bf = *flagp;
  int g0 = blockIdx.x * blockDim.x + threadIdx.x;
  int gs = gridDim.x * blockDim.x;
  for (int i = g0; i < 128 * 260; i += gs) {
    int o = i / 260, c = i - o * 260;
    float s = ldin(sa_g, o, bf) * rsqrtf(ldin(sa_v, o, bf) + 1e-5f);
    float w;
    if (c < 256) w = ldin(sa_w0, o * 259 + c + 3, bf);
    else if (c < 259) w = ldin(sa_w0, o * 259 + (c - 256), bf);
    else w = 0.f;
    w0R[i] = w * s;
  }
  for (int o = g0; o < 128; o += gs) {
    float s0 = ldin(sa_g, o, bf)       * rsqrtf(ldin(sa_v, o, bf)       + 1e-5f);
    float s1 = ldin(sa_g, 128 + o, bf) * rsqrtf(ldin(sa_v, 128 + o, bf) + 1e-5f);
    float s2 = ldin(sa_g, 256 + o, bf) * rsqrtf(ldin(sa_v, 256 + o, bf) + 1e-5f);
    b0[o] = ldin(sa_b, o, bf)       - ldin(sa_m, o, bf)       * s0;
    b1[o] = ldin(sa_b, 128 + o, bf) - ldin(sa_m, 128 + o, bf) * s1;
    b2[o] = ldin(sa_b, 256 + o, bf) - ldin(sa_m, 256 + o, bf) * s2;
    float sc1 = ldin(bn1g, o, bf) * rsqrtf(ldin(bn1v, o, bf) + 1e-5f);
    float sc2 = ldin(bn2g, o, bf) * rsqrtf(ldin(bn2v, o, bf) + 1e-5f);
    d1[o] = (ldin(c1b, o, bf) - ldin(bn1m, o, bf)) * sc1 + ldin(bn1b, o, bf);
    d2[o] = (ldin(c2b, o, bf) - ldin(bn2m, o, bf)) * sc2 + ldin(bn2b, o, bf);
    gngF[o] = ldin(gngI, o, bf);
    gnbF[o] = ldin(gnbI, o, bf);
  }
  for (int i = g0; i < 128 * 128; i += gs) {
    int o = i >> 7, c = i & 127;
    float s1 = ldin(sa_g, 128 + o, bf) * rsqrtf(ldin(sa_v, 128 + o, bf) + 1e-5f);
    float s2 = ldin(sa_g, 256 + o, bf) * rsqrtf(ldin(sa_v, 256 + o, bf) + 1e-5f);
    w1R[i] = ldin(sa_w1, i, bf) * s1;
    w2R[i] = ldin(sa_w2, i, bf) * s2;
    float sc1 = ldin(bn1g, o, bf) * rsqrtf(ldin(bn1v, o, bf) + 1e-5f);
    float sc2 = ldin(bn2g, o, bf) * rsqrtf(ldin(bn2v, o, bf) + 1e-5f);
    c1T[c * 128 + o] = ldin(c1w, i, bf) * sc1;
    c2T[c * 128 + o] = ldin(c2w, i, bf) * sc2;
  }
  for (int i = g0; i < 64 * 128; i += gs) {
    int o = i >> 7, c = i & 127;
    wtT[c * 64 + o] = ldin(wt, i, bf);
    wpT[c * 64 + o] = ldin(wp, i, bf);
    wgT[c * 64 + o] = ldin(wg, i, bf);
  }
  for (int i = g0; i < 43 * 128; i += gs) {
    int o = i >> 7, c = i & 127;
    c3T[c * 43 + o] = ldin(c3w, i, bf);
  }
  for (int i = g0; i < 2048; i += gs) wzF[i] = ldin(wzI, i, bf);
  for (int i = g0; i < 43; i += gs) c3bF[i] = ldin(c3bI, i, bf);
}

// ---------------- feature transpose (B,C,N) -> (B,N,C), store bf16 ----------------
__global__ __launch_bounds__(256) void k_transpose(const void* __restrict__ f, u16* __restrict__ ft,
                                                   const int* __restrict__ flagp) {
  __shared__ u16 tile[32][33];
  int bf = *flagp;
  int b = blockIdx.z, n0 = blockIdx.x * 32, c0 = blockIdx.y * 32;
  int tx = threadIdx.x & 31, ty = threadIdx.x >> 5;
  for (int r = ty; r < 32; r += 8) {
    size_t src = ((size_t)(b * CINx + c0 + r)) * Nx + n0 + tx;
    tile[r][tx] = bf ? ((const u16*)f)[src] : f2b(((const float*)f)[src]);
  }
  __syncthreads();
  for (int r = ty; r < 32; r += 8)
    ft[((size_t)(b * Nx + n0 + r)) * CINx + c0 + tx] = tile[tx][r];
}

// ---------------- FPS: 1 block per batch (exact f32, first-index argmax ties) ----------------
__global__ __launch_bounds__(256) void k_fps(const float* __restrict__ xyzF, float* __restrict__ nxyz) {
  int b = blockIdx.x, t = threadIdx.x;
  const float* xb = xyzF + (size_t)b * Nx * 3;
  float px[8], py[8], pz[8], dist[8];
#pragma unroll
  for (int j = 0; j < 8; ++j) {
    int p = t + 256 * j;
    px[j] = xb[p * 3 + 0];
    py[j] = xb[p * 3 + 1];
    pz[j] = xb[p * 3 + 2];
    dist[j] = 1e10f;
  }
  __shared__ float s_val[4];
  __shared__ int s_idx[4];
  __shared__ int s_far;
  __shared__ int s_inds[Sx];
  int far = 0;
  for (int it = 0; it < Sx; ++it) {
    if (t == 0) s_inds[it] = far;
    float cx = xb[far * 3 + 0];
    float cy = xb[far * 3 + 1];
    float cz = xb[far * 3 + 2];
    float bv = -1.f; int bi = 0;
#pragma unroll
    for (int j = 0; j < 8; ++j) {
      float dx = __fsub_rn(px[j], cx);
      float dy = __fsub_rn(py[j], cy);
      float dz = __fsub_rn(pz[j], cz);
      float d = __fadd_rn(__fadd_rn(__fmul_rn(dx, dx), __fmul_rn(dy, dy)), __fmul_rn(dz, dz));
      float nd = fminf(dist[j], d);
      dist[j] = nd;
      if (nd > bv) { bv = nd; bi = t + 256 * j; }   // j ascending => lowest index kept on tie
    }
#pragma unroll
    for (int off = 32; off; off >>= 1) {
      float ov = __shfl_down(bv, off, 64);
      int   oi = __shfl_down(bi, off, 64);
      if (ov > bv || (ov == bv && oi < bi)) { bv = ov; bi = oi; }
    }
    if ((t & 63) == 0) { s_val[t >> 6] = bv; s_idx[t >> 6] = bi; }
    __syncthreads();
    if (t == 0) {
      for (int k2 = 1; k2 < 4; ++k2)
        if (s_val[k2] > bv || (s_val[k2] == bv && s_idx[k2] < bi)) { bv = s_val[k2]; bi = s_idx[k2]; }
      s_far = bi;
    }
    __syncthreads();
    far = s_far;
  }
  int id = s_inds[t];
  float* o = nxyz + ((size_t)b * Sx + t) * 3;
  o[0] = xb[id * 3 + 0];
  o[1] = xb[id * 3 + 1];
  o[2] = xb[id * 3 + 2];
}

// ---------------- ball query: 1 wave per (b,s) ----------------
__global__ __launch_bounds__(256) void k_ballq(const float* __restrict__ xyzF,
                                               const float* __restrict__ nxyz,
                                               int* __restrict__ idxb) {
  int t = threadIdx.x;
  int wv = t >> 6, lane = t & 63;
  int gs = blockIdx.x * 4 + wv;           // b*S + s
  int b = gs >> 8;
  const float* xb = xyzF + (size_t)b * Nx * 3;
  const float* cen = nxyz + (size_t)gs * 3;
  float cx = cen[0], cy = cen[1], cz = cen[2];
  const float R2 = (float)(0.3 * 0.3);
  int* outp = idxb + (size_t)gs * NSx;
  int have = 0, first = 0;
  bool gotfirst = false;
  for (int ch = 0; ch < Nx / 64 && have < NSx; ++ch) {
    int p = ch * 64 + lane;
    float dx = __fsub_rn(xb[p * 3 + 0], cx);
    float dy = __fsub_rn(xb[p * 3 + 1], cy);
    float dz = __fsub_rn(xb[p * 3 + 2], cz);
    float d2 = __fadd_rn(__fadd_rn(__fmul_rn(dx, dx), __fmul_rn(dy, dy)), __fmul_rn(dz, dz));
    bool hit = d2 < R2;
    unsigned long long m = __ballot(hit);
    if (hit) {
      int pos = have + __popcll(m & ((1ull << lane) - 1ull));
      if (pos < NSx) outp[pos] = p;
    }
    if (!gotfirst && m) { first = ch * 64 + (int)__builtin_ctzll(m); gotfirst = true; }
    have += __popcll(m);
  }
  if (have < NSx && lane >= have && lane < NSx) outp[lane] = first;  // pad with first hit
}

// ---------------- fused gather + 3-layer MLP + maxpool: 1 block per (b,s) ----------------
__global__ __launch_bounds__(256) void k_samlp(
    const u16* __restrict__ featT, const float* __restrict__ xyzF,
    const float* __restrict__ nxyz, const int* __restrict__ idxb,
    const float* __restrict__ w0R, const float* __restrict__ b0v,
    const float* __restrict__ w1R, const float* __restrict__ b1v,
    const float* __restrict__ w2R, const float* __restrict__ b2v,
    float* __restrict__ xT) {
  __shared__ float h0[16 * 260];
  __shared__ float h1[16 * 128];
  __shared__ float h2[16 * 128];
  int s = blockIdx.x, b = blockIdx.y, t = threadIdx.x;
  const int* gidx = idxb + ((size_t)b * Sx + s) * NSx;
  {
    int n = t >> 4, kk = (t & 15) << 4;
    int pn = gidx[n];
    const uint4* rp = (const uint4*)(featT + ((size_t)b * Nx + pn) * CINx + kk);
    uint4 u0 = rp[0], u1 = rp[1];
    float* dst = &h0[n * 260 + kk];
    dst[0]  = b2f((u16)(u0.x & 0xffff)); dst[1]  = b2f((u16)(u0.x >> 16));
    dst[2]  = b2f((u16)(u0.y & 0xffff)); dst[3]  = b2f((u16)(u0.y >> 16));
    dst[4]  = b2f((u16)(u0.z & 0xffff)); dst[5]  = b2f((u16)(u0.z >> 16));
    dst[6]  = b2f((u16)(u0.w & 0xffff)); dst[7]  = b2f((u16)(u0.w >> 16));
    dst[8]  = b2f((u16)(u1.x & 0xffff)); dst[9]  = b2f((u16)(u1.x >> 16));
    dst[10] = b2f((u16)(u1.y & 0xffff)); dst[11] = b2f((u16)(u1.y >> 16));
    dst[12] = b2f((u16)(u1.z & 0xffff)); dst[13] = b2f((u16)(u1.z >> 16));
    dst[14] = b2f((u16)(u1.w & 0xffff)); dst[15] = b2f((u16)(u1.w >> 16));
  }
  if (t < 48) {
    int n2 = t / 3, cc = t - n2 * 3;
    int pn2 = gidx[n2];
    const float* xb = xyzF + (size_t)b * Nx * 3;
    h0[n2 * 260 + 256 + cc] =
        (xb[pn2 * 3 + cc] - nxyz[((size_t)b * Sx + s) * 3 + cc]) / 0.3f;
  } else if (t < 64) {
    h0[(t - 48) * 260 + 259] = 0.f;
  }
  __syncthreads();

  int o = t & 127, nb = (t >> 7) << 3;
  float acc[8];
#pragma unroll
  for (int j = 0; j < 8; ++j) acc[j] = 0.f;
  {
    const float4* wrow = (const float4*)(w0R + o * 260);
    for (int c4 = 0; c4 < 65; ++c4) {
      float4 wv = wrow[c4];
#pragma unroll
      for (int j = 0; j < 8; ++j) {
        const float4 hv = *(const float4*)&h0[(nb + j) * 260 + (c4 << 2)];
        acc[j] = fmaf(hv.x, wv.x, acc[j]);
        acc[j] = fmaf(hv.y, wv.y, acc[j]);
        acc[j] = fmaf(hv.z, wv.z, acc[j]);
        acc[j] = fmaf(hv.w, wv.w, acc[j]);
      }
    }
    float bb = b0v[o];
#pragma unroll
    for (int j = 0; j < 8; ++j) h1[(nb + j) * 128 + o] = fmaxf(acc[j] + bb, 0.f);
  }
  __syncthreads();
#pragma unroll
  for (int j = 0; j < 8; ++j) acc[j] = 0.f;
  {
    const float4* wrow = (const float4*)(w1R + o * 128);
    for (int c4 = 0; c4 < 32; ++c4) {
      float4 wv = wrow[c4];
#pragma unroll
      for (int j = 0; j < 8; ++j) {
        const float4 hv = *(const float4*)&h1[(nb + j) * 128 + (c4 << 2)];
        acc[j] = fmaf(hv.x, wv.x, acc[j]);
        acc[j] = fmaf(hv.y, wv.y, acc[j]);
        acc[j] = fmaf(hv.z, wv.z, acc[j]);
        acc[j] = fmaf(hv.w, wv.w, acc[j]);
      }
    }
    float bb = b1v[o];
#pragma unroll
    for (int j = 0; j < 8; ++j) h2[(nb + j) * 128 + o] = fmaxf(acc[j] + bb, 0.f);
  }
  __syncthreads();
#pragma unroll
  for (int j = 0; j < 8; ++j) acc[j] = 0.f;
  {
    const float4* wrow = (const float4*)(w2R + o * 128);
    for (int c4 = 0; c4 < 32; ++c4) {
      float4 wv = wrow[c4];
#pragma unroll
      for (int j = 0; j < 8; ++j) {
        const float4 hv = *(const float4*)&h2[(nb + j) * 128 + (c4 << 2)];
        acc[j] = fmaf(hv.x, wv.x, acc[j]);
        acc[j] = fmaf(hv.y, wv.y, acc[j]);
        acc[j] = fmaf(hv.z, wv.z, acc[j]);
        acc[j] = fmaf(hv.w, wv.w, acc[j]);
      }
    }
    float bb = b2v[o];
#pragma unroll
    for (int j = 0; j < 8; ++j) h1[(nb + j) * 128 + o] = fmaxf(acc[j] + bb, 0.f);
  }
  __syncthreads();
  if (t < 128) {
    float m = h1[t];
#pragma unroll
    for (int n2 = 1; n2 < 16; ++n2) m = fmaxf(m, h1[n2 * 128 + t]);
    xT[((size_t)b * Sx + s) * 128 + t] = m;
  }
}

// ---------------- t/p/g GEMMs + attention partial sums ----------------
__global__ __launch_bounds__(256) void k_tpg(const float* __restrict__ xT,
                                             const float* __restrict__ wtT,
                                             const float* __restrict__ wpT,
                                             const float* __restrict__ wgT,
                                             float* __restrict__ tbuf,
                                             float* __restrict__ att) {
  __shared__ float xs[64][129];
  int b = blockIdx.y, s0 = blockIdx.x * 64, t = threadIdx.x;
  {
    int r = t >> 2, part = (t & 3) * 32;
    const float4* src = (const float4*)(xT + ((size_t)b * Sx + s0 + r) * 128 + part);
#pragma unroll
    for (int q = 0; q < 8; ++q) {
      float4 v = src[q];
      xs[r][part + q * 4 + 0] = v.x;
      xs[r][part + q * 4 + 1] = v.y;
      xs[r][part + q * 4 + 2] = v.z;
      xs[r][part + q * 4 + 3] = v.w;
    }
  }
  __syncthreads();
  int sg = t & 15, og = t >> 4;
  float ta[16], pa[16], ga[16];
#pragma unroll
  for (int k = 0; k < 16; ++k) { ta[k] = 0.f; pa[k] = 0.f; ga[k] = 0.f; }
  for (int c = 0; c < 128; ++c) {
    float xv[4];
#pragma unroll
    for (int j = 0; j < 4; ++j) xv[j] = xs[sg * 4 + j][c];
    float4 wtv = *(const float4*)(wtT + c * 64 + og * 4);
    float4 wpv = *(const float4*)(wpT + c * 64 + og * 4);
    float4 wgv = *(const float4*)(wgT + c * 64 + og * 4);
    float wa[4] = {wtv.x, wtv.y, wtv.z, wtv.w};
    float wb[4] = {wpv.x, wpv.y, wpv.z, wpv.w};
    float wc[4] = {wgv.x, wgv.y, wgv.z, wgv.w};
#pragma unroll
    for (int i = 0; i < 4; ++i)
#pragma unroll
      for (int j = 0; j < 4; ++j) {
        ta[i * 4 + j] = fmaf(wa[i], xv[j], ta[i * 4 + j]);
        pa[i * 4 + j] = fmaf(wb[i], xv[j], pa[i * 4 + j]);
        ga[i * 4 + j] = fmaf(wc[i], xv[j], ga[i * 4 + j]);
      }
  }
#pragma unroll
  for (int i = 0; i < 4; ++i)
#pragma unroll
    for (int j = 0; j < 4; ++j)
      tbuf[((size_t)b * 64 + og * 4 + i) * 256 + s0 + sg * 4 + j] = ta[i * 4 + j];
  float pv = 0.f;
#pragma unroll
  for (int k = 0; k < 16; ++k) pv += pa[k] * ga[k];
#pragma unroll
  for (int off = 32; off; off >>= 1) pv += __shfl_down(pv, off, 64);
  if ((t & 63) == 0) atomicAdd(att + b * 4 + (t >> 6), pv);  // wave w <=> group w
}

__device__ __forceinline__ float blocksum(float v, volatile float* red, int t) {
#pragma unroll
  for (int off = 32; off; off >>= 1) v += __shfl_down(v, off, 64);
  __syncthreads();
  if ((t & 63) == 0) red[t >> 6] = v;
  __syncthreads();
  return red[0] + red[1] + red[2] + red[3];
}

// ---------------- att*t, wz einsum, GroupNorm, residual ----------------
__global__ __launch_bounds__(256) void k_gn(const float* __restrict__ tbuf,
                                            const float* __restrict__ att,
                                            const float* __restrict__ wzF,
                                            const float* __restrict__ gngF,
                                            const float* __restrict__ gnbF,
                                            const float* __restrict__ xT,
                                            float* __restrict__ yT) {
  __shared__ float tg[16][256];
  __shared__ float wzs[32][16];
  __shared__ float red[4];
  int g = blockIdx.x, b = blockIdx.y, t = threadIdx.x;
  {
    int n = t >> 4, kk = (t & 15) * 16;
    const float4* src = (const float4*)(tbuf + ((size_t)b * 64 + g * 16 + n) * 256 + kk);
#pragma unroll
    for (int q = 0; q < 4; ++q) {
      float4 v = src[q];
      tg[n][kk + q * 4 + 0] = v.x;
      tg[n][kk + q * 4 + 1] = v.y;
      tg[n][kk + q * 4 + 2] = v.z;
      tg[n][kk + q * 4 + 3] = v.w;
    }
  }
  for (int i = t; i < 512; i += 256)
    wzs[i >> 4][i & 15] = wzF[(g * 32 + (i >> 4)) * 16 + (i & 15)];
  __syncthreads();
  float attv = att[b * 4 + g];
  int s = t;
  float yv[32];
#pragma unroll
  for (int o = 0; o < 32; ++o) yv[o] = 0.f;
  for (int c = 0; c < 16; ++c) {
    float tv = attv * tg[c][s];
#pragma unroll
    for (int o = 0; o < 32; ++o) yv[o] = fmaf(wzs[o][c], tv, yv[o]);
  }
  float ls = 0.f;
#pragma unroll
  for (int o = 0; o < 32; ++o) ls += yv[o];
  float mu = blocksum(ls, red, t) * (1.f / 8192.f);
  float lq = 0.f;
#pragma unroll
  for (int o = 0; o < 32; ++o) { float d = yv[o] - mu; lq = fmaf(d, d, lq); }
  float var = blocksum(lq, red, t) * (1.f / 8192.f);
  float rs = rsqrtf(var + 1e-5f);
  const float* xrow = xT + ((size_t)b * Sx + s) * 128 + g * 32;
  float* yrow = yT + ((size_t)b * Sx + s) * 128 + g * 32;
#pragma unroll
  for (int o = 0; o < 32; ++o) {
    int ch = g * 32 + o;
    yrow[o] = (yv[o] - mu) * rs * gngF[ch] + gnbF[ch] + xrow[o];
  }
}

// ---------------- FFN + box-head output assembly ----------------
__global__ __launch_bounds__(256) void k_ffn(const float* __restrict__ yT,
                                             const float* __restrict__ c1T, const float* __restrict__ d1,
                                             const float* __restrict__ c2T, const float* __restrict__ d2,
                                             const float* __restrict__ c3T, const float* __restrict__ c3bF,
                                             const float* __restrict__ nxyz,
                                             void* __restrict__ outp,
                                             const int* __restrict__ flagp) {
  __shared__ float ys[32][132];
  __shared__ float h1s[32][132];
  __shared__ float h2s[32][132];
  __shared__ float nets[32][44];
  int bf = *flagp;
  int b = blockIdx.y, s0 = blockIdx.x * 32, t = threadIdx.x;
  {
    int r = t >> 3, part = (t & 7) * 16;
    const float4* src = (const float4*)(yT + ((size_t)b * Sx + s0 + r) * 128 + part);
#pragma unroll
    for (int q = 0; q < 4; ++q) *(float4*)&ys[r][part + q * 4] = src[q];
  }
  __syncthreads();
  int o0 = (t & 31) * 4, sl0 = (t >> 5) * 4;
  float acc[16];
#pragma unroll
  for (int k = 0; k < 16; ++k) acc[k] = 0.f;
  for (int c = 0; c < 128; ++c) {
    float4 wv = *(const float4*)(c1T + c * 128 + o0);
    float yv[4];
#pragma unroll
    for (int j = 0; j < 4; ++j) yv[j] = ys[sl0 + j][c];
#pragma unroll
    for (int j = 0; j < 4; ++j) {
      acc[0 * 4 + j] = fmaf(wv.x, yv[j], acc[0 * 4 + j]);
      acc[1 * 4 + j] = fmaf(wv.y, yv[j], acc[1 * 4 + j]);
      acc[2 * 4 + j] = fmaf(wv.z, yv[j], acc[2 * 4 + j]);
      acc[3 * 4 + j] = fmaf(wv.w, yv[j], acc[3 * 4 + j]);
    }
  }
  {
    float4 dv = *(const float4*)(d1 + o0);
    float db[4] = {dv.x, dv.y, dv.z, dv.w};
#pragma unroll
    for (int i = 0; i < 4; ++i)
#pragma unroll
      for (int j = 0; j < 4; ++j)
        h1s[sl0 + j][o0 + i] = fmaxf(acc[i * 4 + j] + db[i], 0.f);
  }
  __syncthreads();
#pragma unroll
  for (int k = 0; k < 16; ++k) acc[k] = 0.f;
  for (int c = 0; c < 128; ++c) {
    float4 wv = *(const float4*)(c2T + c * 128 + o0);
    float yv[4];
#pragma unroll
    for (int j = 0; j < 4; ++j) yv[j] = h1s[sl0 + j][c];
#pragma unroll
    for (int j = 0; j < 4; ++j) {
      acc[0 * 4 + j] = fmaf(wv.x, yv[j], acc[0 * 4 + j]);
      acc[1 * 4 + j] = fmaf(wv.y, yv[j], acc[1 * 4 + j]);
      acc[2 * 4 + j] = fmaf(wv.z, yv[j], acc[2 * 4 + j]);
      acc[3 * 4 + j] = fmaf(wv.w, yv[j], acc[3 * 4 + j]);
    }
  }
  {
    float4 dv = *(const float4*)(d2 + o0);
    float db[4] = {dv.x, dv.y, dv.z, dv.w};
#pragma unroll
    for (int i = 0; i < 4; ++i)
#pragma unroll
      for (int j = 0; j < 4; ++j)
        h2s[sl0 + j][o0 + i] = fmaxf(acc[i * 4 + j] + db[i], 0.f);
  }
  __syncthreads();
  for (int f = t; f < 43 * 32; f += 256) {
    int o = f >> 5, s = f & 31;
    float a = c3bF[o];
    for (int c4 = 0; c4 < 32; ++c4) {
      float4 hv = *(const float4*)&h2s[s][c4 * 4];
      a = fmaf(hv.x, c3T[(c4 * 4 + 0) * 43 + o], a);
      a = fmaf(hv.y, c3T[(c4 * 4 + 1) * 43 + o], a);
      a = fmaf(hv.z, c3T[(c4 * 4 + 2) * 43 + o], a);
      a = fmaf(hv.w, c3T[(c4 * 4 + 3) * 43 + o], a);
    }
    nets[s][o] = a;
  }
  __syncthreads();
  const float PI12 = (float)(M_PI / 12.0);
  for (int f = t; f < 55 * 32; f += 256) {
    int s = f / 55, kk = f - s * 55;
    float v;
    if (kk < 5) {
      v = nets[s][kk];
      if (kk >= 2) v += nxyz[((size_t)b * Sx + s0 + s) * 3 + (kk - 2)];
    } else if (kk < 31) v = nets[s][kk];
    else if (kk < 43) v = nets[s][kk - 12] * PI12;
    else v = nets[s][kk - 12];
    size_t oi = ((size_t)b * Sx + s0 + s) * 55 + kk;
    if (bf) ((u16*)outp)[oi] = f2b(v);
    else    ((float*)outp)[oi] = v;
  }
}

extern "C" void kernel_launch(void* const* d_in, const int* in_sizes, int n_in,
                              void* d_out, int out_size, void* d_ws, size_t ws_size,
                              hipStream_t stream) {
  char* w = (char*)d_ws;
  u16*   featT = (u16*)(w + OFF_FEATT);
  float* xT    = (float*)(w + OFF_XT);
  float* tbuf  = (float*)(w + OFF_T);
  float* yT    = (float*)(w + OFF_YT);
  float* nxyz  = (float*)(w + OFF_NXYZ);
  int*   idxb  = (int*)(w + OFF_IDX);
  float* att   = (float*)(w + OFF_ATT);
  float* w0R   = (float*)(w + OFF_W0R);
  float* b0    = (float*)(w + OFF_B0);
  float* w1R   = (float*)(w + OFF_W1R);
  float* b1    = (float*)(w + OFF_B1);
  float* w2R   = (float*)(w + OFF_W2R);
  float* b2    = (float*)(w + OFF_B2);
  float* wtT   = (float*)(w + OFF_WTT);
  float* wpT   = (float*)(w + OFF_WPT);
  float* wgT   = (float*)(w + OFF_WGT);
  float* c1T   = (float*)(w + OFF_C1T);
  float* d1    = (float*)(w + OFF_D1);
  float* c2T   = (float*)(w + OFF_C2T);
  float* d2    = (float*)(w + OFF_D2);
  float* c3T   = (float*)(w + OFF_C3T);
  float* xyzF  = (float*)(w + OFF_XYZF);
  float* wzF   = (float*)(w + OFF_WZF);
  float* gngF  = (float*)(w + OFF_GNG);
  float* gnbF  = (float*)(w + OFF_GNB);
  float* c3bF  = (float*)(w + OFF_C3B);
  int*   flag  = (int*)(w + OFF_FLAG);

  hipMemsetAsync(w + OFF_ATT, 0, 512, stream);
  k_sniff<<<1, 256, 0, stream>>>((const u32*)d_in[0], flag);
  k_cvt<<<(Bx * Nx * 3 + 255) / 256, 256, 0, stream>>>(d_in[0], xyzF, flag);
  k_prep<<<64, 256, 0, stream>>>(d_in[2], d_in[3], d_in[4], d_in[5], d_in[6], d_in[7], d_in[8],
                                 d_in[9], d_in[10], d_in[11], d_in[12], d_in[13], d_in[14],
                                 d_in[15], d_in[16], d_in[17], d_in[18], d_in[19], d_in[20],
                                 d_in[21], d_in[22], d_in[23], d_in[24], d_in[25], d_in[26],
                                 d_in[27], d_in[28],
                                 w0R, b0, w1R, b1, w2R, b2, wtT, wpT, wgT,
                                 c1T, d1, c2T, d2, c3T, wzF, gngF, gnbF, c3bF, flag);
  k_transpose<<<dim3(Nx / 32, CINx / 32, Bx), 256, 0, stream>>>(d_in[1], featT, flag);
  k_fps<<<Bx, 256, 0, stream>>>(xyzF, nxyz);
  k_ballq<<<(Bx * Sx) / 4, 256, 0, stream>>>(xyzF, nxyz, idxb);
  k_samlp<<<dim3(Sx, Bx), 256, 0, stream>>>(featT, xyzF, nxyz, idxb,
                                            w0R, b0, w1R, b1, w2R, b2, xT);
  k_tpg<<<dim3(4, Bx), 256, 0, stream>>>(xT, wtT, wpT, wgT, tbuf, att);
  k_gn<<<dim3(4, Bx), 256, 0, stream>>>(tbuf, att, wzF, gngF, gnbF, xT, yT);
  k_ffn<<<dim3(8, Bx), 256, 0, stream>>>(yT, c1T, d1, c2T, d2, c3T, c3bF, nxyz,
                                         d_out, flag);
}

// Round 3
// 653.971 us; speedup vs baseline: 1.6628x; 1.6628x over previous
//
#include <hip/hip_runtime.h>
#include <hip/hip_bf16.h>
#include <math.h>

#define Bx   32
#define Nx   2048
#define Sx   256
#define NSx  16
#define CINx 256

typedef unsigned short u16;
typedef unsigned int   u32;
typedef short bf16x8 __attribute__((ext_vector_type(8)));
typedef float f32x4  __attribute__((ext_vector_type(4)));

__device__ __forceinline__ float b2f(u16 u) {
  union { u32 i; float f; } v; v.i = ((u32)u) << 16; return v.f;
}
__device__ __forceinline__ u16 f2b(float x) {  // RNE f32->bf16
  u32 u = __float_as_uint(x);
  u32 r = (u + 0x7FFFu + ((u >> 16) & 1u)) >> 16;
  return (u16)r;
}
// dtype-adaptive input load: bf=1 -> buffer holds bf16, bf=0 -> f32
__device__ __forceinline__ float ldin(const void* p, int i, int bf) {
  return bf ? b2f(((const u16*)p)[i]) : ((const float*)p)[i];
}

// ---------------- workspace layout (bytes) ----------------
#define OFF_FEATT 0                      // bf16 (B,N,C)   33554432
#define OFF_XT    (33554432)             // f32 (B,S,128)   4194304
#define OFF_T     (OFF_XT + 4194304)     // f32 (B,64,S)    2097152
#define OFF_YT    (OFF_T + 2097152)      // f32 (B,S,128)   4194304
#define OFF_NXYZ  (OFF_YT + 4194304)     // f32 (B,S,3)       98304
#define OFF_IDX   (OFF_NXYZ + 98304)     // i32 (B,S,16)     524288
#define OFF_ATT   (OFF_IDX + 524288)     // f32 (B,4)           512
#define OFF_W0F   (OFF_ATT + 512)        // bf16 frag-packed 9*8*64*8 = 73728B (slot 133120)
#define OFF_B0    (OFF_W0F + 133120)
#define OFF_W1F   (OFF_B0 + 512)         // bf16 frag-packed 4*8*64*8 = 32768B (slot 65536)
#define OFF_B1    (OFF_W1F + 65536)
#define OFF_W2F   (OFF_B1 + 512)
#define OFF_B2    (OFF_W2F + 65536)
#define OFF_WTT   (OFF_B2 + 512)         // f32 128x64 (c-major)
#define OFF_WPT   (OFF_WTT + 32768)
#define OFF_WGT   (OFF_WPT + 32768)
#define OFF_C1T   (OFF_WGT + 32768)      // f32 128x128 (c-major, bn-folded)
#define OFF_D1    (OFF_C1T + 65536)
#define OFF_C2T   (OFF_D1 + 512)
#define OFF_D2    (OFF_C2T + 65536)
#define OFF_C3T   (OFF_D2 + 512)         // f32 128x43 (c-major)
#define OFF_XYZF  (OFF_C3T + 22016)      // f32 (B,N,3)      786432
#define OFF_WZF   (OFF_XYZF + 786432)    // f32 128x16         8192
#define OFF_GNG   (OFF_WZF + 8192)       // f32 128             512
#define OFF_GNB   (OFF_GNG + 512)
#define OFF_C3B   (OFF_GNB + 512)        // f32 43              512
#define OFF_FLAG  (OFF_C3B + 512)        // i32                 512

// ---------------- dtype sniff: decide bf16 vs f32 inputs from xyz bits ----------------
__global__ __launch_bounds__(256) void k_sniff(const u32* __restrict__ w, int* __restrict__ flag) {
  __shared__ int cnt;
  int t = threadIdx.x;
  if (t == 0) cnt = 0;
  __syncthreads();
  u32 x = w[t];
  int e_lo = (x >> 7) & 0xFF;                 // exponent field if low u16 were a bf16
  if (e_lo >= 100 && e_lo <= 140) atomicAdd(&cnt, 1);
  __syncthreads();
  if (t == 0) *flag = (cnt > 128) ? 1 : 0;    // 1 = inputs are bf16
}

// ---------------- xyz -> f32 staging ----------------
__global__ __launch_bounds__(256) void k_cvt(const void* __restrict__ xyz, float* __restrict__ xyzF,
                                             const int* __restrict__ flagp) {
  int bf = *flagp;
  int i = blockIdx.x * 256 + threadIdx.x;
  if (i < Bx * Nx * 3) xyzF[i] = ldin(xyz, i, bf);
}

// ---------------- prep: fold BN into weights, pack MFMA frags, transpose layouts ----------------
// B-frag layout (16x16x32 bf16): lane l holds B[k=kt*32+(l>>4)*8+j][n=nt*16+(l&15)], j=0..7
// stored at wF[((kt*NT+nt)*64 + l)*8 + j]  -> one coalesced 16B load per lane.
__global__ __launch_bounds__(256) void k_prep(
    const void* sa_w0, const void* sa_w1, const void* sa_w2,
    const void* sa_g,  const void* sa_b,  const void* sa_m, const void* sa_v,
    const void* wt, const void* wp, const void* wg, const void* wzI,
    const void* gngI, const void* gnbI,
    const void* c1w, const void* c1b,
    const void* bn1g, const void* bn1b, const void* bn1m, const void* bn1v,
    const void* c2w, const void* c2b,
    const void* bn2g, const void* bn2b, const void* bn2m, const void* bn2v,
    const void* c3w, const void* c3bI,
    u16* __restrict__ w0F, float* __restrict__ b0, u16* __restrict__ w1F, float* __restrict__ b1,
    u16* __restrict__ w2F, float* __restrict__ b2,
    float* __restrict__ wtT, float* __restrict__ wpT, float* __restrict__ wgT,
    float* __restrict__ c1T, float* __restrict__ d1, float* __restrict__ c2T, float* __restrict__ d2,
    float* __restrict__ c3T, float* __restrict__ wzF, float* __restrict__ gngF,
    float* __restrict__ gnbF, float* __restrict__ c3bF,
    const int* __restrict__ flagp) {
  int bf = *flagp;
  int g0 = blockIdx.x * blockDim.x + threadIdx.x;
  int gs = gridDim.x * blockDim.x;
  // layer-1 frags: K-tiles 0..7 = features (input cols 3..258), tile 8 = rel-xyz (cols 0..2) + zero pad
  for (int i = g0; i < 9 * 8 * 64 * 8; i += gs) {
    int j = i & 7, lane = (i >> 3) & 63, nt = (i >> 9) & 7, kt = i >> 12;
    int o = nt * 16 + (lane & 15);
    int c = kt * 32 + (lane >> 4) * 8 + j;
    float s = ldin(sa_g, o, bf) * rsqrtf(ldin(sa_v, o, bf) + 1e-5f);
    float w;
    if (c < 256) w = ldin(sa_w0, o * 259 + 3 + c, bf);
    else if (c < 259) w = ldin(sa_w0, o * 259 + (c - 256), bf);
    else w = 0.f;
    w0F[i] = f2b(w * s);
  }
  for (int i = g0; i < 4 * 8 * 64 * 8; i += gs) {
    int j = i & 7, lane = (i >> 3) & 63, nt = (i >> 9) & 7, kt = i >> 12;
    int o = nt * 16 + (lane & 15);
    int c = kt * 32 + (lane >> 4) * 8 + j;
    float s1 = ldin(sa_g, 128 + o, bf) * rsqrtf(ldin(sa_v, 128 + o, bf) + 1e-5f);
    float s2 = ldin(sa_g, 256 + o, bf) * rsqrtf(ldin(sa_v, 256 + o, bf) + 1e-5f);
    w1F[i] = f2b(ldin(sa_w1, o * 128 + c, bf) * s1);
    w2F[i] = f2b(ldin(sa_w2, o * 128 + c, bf) * s2);
  }
  for (int o = g0; o < 128; o += gs) {
    float s0 = ldin(sa_g, o, bf)       * rsqrtf(ldin(sa_v, o, bf)       + 1e-5f);
    float s1 = ldin(sa_g, 128 + o, bf) * rsqrtf(ldin(sa_v, 128 + o, bf) + 1e-5f);
    float s2 = ldin(sa_g, 256 + o, bf) * rsqrtf(ldin(sa_v, 256 + o, bf) + 1e-5f);
    b0[o] = ldin(sa_b, o, bf)       - ldin(sa_m, o, bf)       * s0;
    b1[o] = ldin(sa_b, 128 + o, bf) - ldin(sa_m, 128 + o, bf) * s1;
    b2[o] = ldin(sa_b, 256 + o, bf) - ldin(sa_m, 256 + o, bf) * s2;
    float sc1 = ldin(bn1g, o, bf) * rsqrtf(ldin(bn1v, o, bf) + 1e-5f);
    float sc2 = ldin(bn2g, o, bf) * rsqrtf(ldin(bn2v, o, bf) + 1e-5f);
    d1[o] = (ldin(c1b, o, bf) - ldin(bn1m, o, bf)) * sc1 + ldin(bn1b, o, bf);
    d2[o] = (ldin(c2b, o, bf) - ldin(bn2m, o, bf)) * sc2 + ldin(bn2b, o, bf);
    gngF[o] = ldin(gngI, o, bf);
    gnbF[o] = ldin(gnbI, o, bf);
  }
  for (int i = g0; i < 128 * 128; i += gs) {
    int o = i >> 7, c = i & 127;
    float sc1 = ldin(bn1g, o, bf) * rsqrtf(ldin(bn1v, o, bf) + 1e-5f);
    float sc2 = ldin(bn2g, o, bf) * rsqrtf(ldin(bn2v, o, bf) + 1e-5f);
    c1T[c * 128 + o] = ldin(c1w, i, bf) * sc1;
    c2T[c * 128 + o] = ldin(c2w, i, bf) * sc2;
  }
  for (int i = g0; i < 64 * 128; i += gs) {
    int o = i >> 7, c = i & 127;
    wtT[c * 64 + o] = ldin(wt, i, bf);
    wpT[c * 64 + o] = ldin(wp, i, bf);
    wgT[c * 64 + o] = ldin(wg, i, bf);
  }
  for (int i = g0; i < 43 * 128; i += gs) {
    int o = i >> 7, c = i & 127;
    c3T[c * 43 + o] = ldin(c3w, i, bf);
  }
  for (int i = g0; i < 2048; i += gs) wzF[i] = ldin(wzI, i, bf);
  for (int i = g0; i < 43; i += gs) c3bF[i] = ldin(c3bI, i, bf);
}

// ---------------- feature transpose (B,C,N) -> (B,N,C), store bf16 ----------------
__global__ __launch_bounds__(256) void k_transpose(const void* __restrict__ f, u16* __restrict__ ft,
                                                   const int* __restrict__ flagp) {
  __shared__ u16 tile[32][33];
  int bf = *flagp;
  int b = blockIdx.z, n0 = blockIdx.x * 32, c0 = blockIdx.y * 32;
  int tx = threadIdx.x & 31, ty = threadIdx.x >> 5;
  for (int r = ty; r < 32; r += 8) {
    size_t src = ((size_t)(b * CINx + c0 + r)) * Nx + n0 + tx;
    tile[r][tx] = bf ? ((const u16*)f)[src] : f2b(((const float*)f)[src]);
  }
  __syncthreads();
  for (int r = ty; r < 32; r += 8)
    ft[((size_t)(b * Nx + n0 + r)) * CINx + c0 + tx] = tile[tx][r];
}

// ---------------- FPS: 1 block per batch (exact f32, first-index argmax ties) ----------------
__global__ __launch_bounds__(256) void k_fps(const float* __restrict__ xyzF, float* __restrict__ nxyz) {
  int b = blockIdx.x, t = threadIdx.x;
  const float* xb = xyzF + (size_t)b * Nx * 3;
  float px[8], py[8], pz[8], dist[8];
#pragma unroll
  for (int j = 0; j < 8; ++j) {
    int p = t + 256 * j;
    px[j] = xb[p * 3 + 0];
    py[j] = xb[p * 3 + 1];
    pz[j] = xb[p * 3 + 2];
    dist[j] = 1e10f;
  }
  __shared__ float s_val[4];
  __shared__ int s_idx[4];
  __shared__ int s_far;
  __shared__ int s_inds[Sx];
  int far = 0;
  for (int it = 0; it < Sx; ++it) {
    if (t == 0) s_inds[it] = far;
    float cx = xb[far * 3 + 0];
    float cy = xb[far * 3 + 1];
    float cz = xb[far * 3 + 2];
    float bv = -1.f; int bi = 0;
#pragma unroll
    for (int j = 0; j < 8; ++j) {
      float dx = __fsub_rn(px[j], cx);
      float dy = __fsub_rn(py[j], cy);
      float dz = __fsub_rn(pz[j], cz);
      float d = __fadd_rn(__fadd_rn(__fmul_rn(dx, dx), __fmul_rn(dy, dy)), __fmul_rn(dz, dz));
      float nd = fminf(dist[j], d);
      dist[j] = nd;
      if (nd > bv) { bv = nd; bi = t + 256 * j; }   // j ascending => lowest index kept on tie
    }
#pragma unroll
    for (int off = 32; off; off >>= 1) {
      float ov = __shfl_down(bv, off, 64);
      int   oi = __shfl_down(bi, off, 64);
      if (ov > bv || (ov == bv && oi < bi)) { bv = ov; bi = oi; }
    }
    if ((t & 63) == 0) { s_val[t >> 6] = bv; s_idx[t >> 6] = bi; }
    __syncthreads();
    if (t == 0) {
      for (int k2 = 1; k2 < 4; ++k2)
        if (s_val[k2] > bv || (s_val[k2] == bv && s_idx[k2] < bi)) { bv = s_val[k2]; bi = s_idx[k2]; }
      s_far = bi;
    }
    __syncthreads();
    far = s_far;
  }
  int id = s_inds[t];
  float* o = nxyz + ((size_t)b * Sx + t) * 3;
  o[0] = xb[id * 3 + 0];
  o[1] = xb[id * 3 + 1];
  o[2] = xb[id * 3 + 2];
}

// ---------------- ball query: 1 wave per (b,s) ----------------
__global__ __launch_bounds__(256) void k_ballq(const float* __restrict__ xyzF,
                                               const float* __restrict__ nxyz,
                                               int* __restrict__ idxb) {
  int t = threadIdx.x;
  int wv = t >> 6, lane = t & 63;
  int gs = blockIdx.x * 4 + wv;           // b*S + s
  int b = gs >> 8;
  const float* xb = xyzF + (size_t)b * Nx * 3;
  const float* cen = nxyz + (size_t)gs * 3;
  float cx = cen[0], cy = cen[1], cz = cen[2];
  const float R2 = (float)(0.3 * 0.3);
  int* outp = idxb + (size_t)gs * NSx;
  int have = 0, first = 0;
  bool gotfirst = false;
  for (int ch = 0; ch < Nx / 64 && have < NSx; ++ch) {
    int p = ch * 64 + lane;
    float dx = __fsub_rn(xb[p * 3 + 0], cx);
    float dy = __fsub_rn(xb[p * 3 + 1], cy);
    float dz = __fsub_rn(xb[p * 3 + 2], cz);
    float d2 = __fadd_rn(__fadd_rn(__fmul_rn(dx, dx), __fmul_rn(dy, dy)), __fmul_rn(dz, dz));
    bool hit = d2 < R2;
    unsigned long long m = __ballot(hit);
    if (hit) {
      int pos = have + __popcll(m & ((1ull << lane) - 1ull));
      if (pos < NSx) outp[pos] = p;
    }
    if (!gotfirst && m) { first = ch * 64 + (int)__builtin_ctzll(m); gotfirst = true; }
    have += __popcll(m);
  }
  if (have < NSx && lane >= have && lane < NSx) outp[lane] = first;  // pad with first hit
}

// ---------------- SA-MLP via bf16 MFMA: 1 wave per (b,s) ----------------
// A-frag (M=16,K=32): lane holds A[m=lane&15][k=q*8+j]  (16 contiguous bytes)
// C/D: col=lane&15, row=q*4+reg
__global__ __launch_bounds__(256) void k_samlp(
    const u16* __restrict__ featT, const float* __restrict__ xyzF,
    const float* __restrict__ nxyz, const int* __restrict__ idxb,
    const u16* __restrict__ w0F, const float* __restrict__ b0v,
    const u16* __restrict__ w1F, const float* __restrict__ b1v,
    const u16* __restrict__ w2F, const float* __restrict__ b2v,
    float* __restrict__ xT) {
  // per-wave LDS: ht[16][32] tail tile | hA[16][136] | hB[16][136]  (all bf16)
  __shared__ __align__(16) u16 lds[4][16 * 32 + 2 * 16 * 136];
  int t = threadIdx.x, w = t >> 6, lane = t & 63;
  int s = blockIdx.x * 4 + w, b = blockIdx.y;
  u16* ht = &lds[w][0];
  u16* hA = &lds[w][512];
  u16* hB = &lds[w][512 + 2176];
  const int* gidx = idxb + ((size_t)b * Sx + s) * NSx;
  int m = lane & 15, q = lane >> 4;
  int pn = gidx[m];
  const float* cen = nxyz + ((size_t)b * Sx + s) * 3;
  // tail tile: cols 0..2 = rel-xyz, cols 3..31 = 0 (disjoint writes, no WAW)
  for (int i = lane; i < 16 * 32; i += 64)
    if ((i & 31) >= 3) ht[i] = 0;
  if (lane < 48) {
    int n2 = lane / 3, cc = lane - n2 * 3;
    int pn2 = gidx[n2];
    float v = (xyzF[((size_t)b * Nx + pn2) * 3 + cc] - cen[cc]) * (1.0f / 0.3f);
    ht[n2 * 32 + cc] = f2b(v);
  }
  __syncthreads();

  const bf16x8* wf0 = (const bf16x8*)w0F;
  const bf16x8* wf1 = (const bf16x8*)w1F;
  const bf16x8* wf2 = (const bf16x8*)w2F;
  f32x4 acc[8];

  // ---- layer 1: [16x288] x [288x128] ----
#pragma unroll
  for (int nt = 0; nt < 8; ++nt) acc[nt] = (f32x4){0.f, 0.f, 0.f, 0.f};
  const u16* arow = featT + ((size_t)b * Nx + pn) * CINx + q * 8;
#pragma unroll
  for (int kt = 0; kt < 9; ++kt) {
    bf16x8 a = (kt < 8) ? *(const bf16x8*)(arow + kt * 32)
                        : *(const bf16x8*)(ht + m * 32 + q * 8);
#pragma unroll
    for (int nt = 0; nt < 8; ++nt)
      acc[nt] = __builtin_amdgcn_mfma_f32_16x16x32_bf16(a, wf0[(kt * 8 + nt) * 64 + lane], acc[nt], 0, 0, 0);
  }
#pragma unroll
  for (int nt = 0; nt < 8; ++nt) {
    float bb = b0v[nt * 16 + m];
#pragma unroll
    for (int r = 0; r < 4; ++r)
      hA[(q * 4 + r) * 136 + nt * 16 + m] = f2b(fmaxf(acc[nt][r] + bb, 0.f));
  }
  __syncthreads();

  // ---- layer 2: [16x128] x [128x128] ----
#pragma unroll
  for (int nt = 0; nt < 8; ++nt) acc[nt] = (f32x4){0.f, 0.f, 0.f, 0.f};
#pragma unroll
  for (int kt = 0; kt < 4; ++kt) {
    bf16x8 a = *(const bf16x8*)(hA + m * 136 + kt * 32 + q * 8);
#pragma unroll
    for (int nt = 0; nt < 8; ++nt)
      acc[nt] = __builtin_amdgcn_mfma_f32_16x16x32_bf16(a, wf1[(kt * 8 + nt) * 64 + lane], acc[nt], 0, 0, 0);
  }
#pragma unroll
  for (int nt = 0; nt < 8; ++nt) {
    float bb = b1v[nt * 16 + m];
#pragma unroll
    for (int r = 0; r < 4; ++r)
      hB[(q * 4 + r) * 136 + nt * 16 + m] = f2b(fmaxf(acc[nt][r] + bb, 0.f));
  }
  __syncthreads();

  // ---- layer 3 + maxpool ----
#pragma unroll
  for (int nt = 0; nt < 8; ++nt) acc[nt] = (f32x4){0.f, 0.f, 0.f, 0.f};
#pragma unroll
  for (int kt = 0; kt < 4; ++kt) {
    bf16x8 a = *(const bf16x8*)(hB + m * 136 + kt * 32 + q * 8);
#pragma unroll
    for (int nt = 0; nt < 8; ++nt)
      acc[nt] = __builtin_amdgcn_mfma_f32_16x16x32_bf16(a, wf2[(kt * 8 + nt) * 64 + lane], acc[nt], 0, 0, 0);
  }
  float* xrow = xT + ((size_t)b * Sx + s) * 128;
#pragma unroll
  for (int nt = 0; nt < 8; ++nt) {
    float vm = fmaxf(fmaxf(acc[nt][0], acc[nt][1]), fmaxf(acc[nt][2], acc[nt][3]));
    vm = fmaxf(vm, __shfl_xor(vm, 16, 64));
    vm = fmaxf(vm, __shfl_xor(vm, 32, 64));   // max over all 16 neighbors
    float v = fmaxf(vm + b2v[nt * 16 + m], 0.f);  // relu(max+b) == max(relu(x+b))
    if (q == 0) xrow[nt * 16 + m] = v;
  }
}

// ---------------- t/p/g GEMMs + attention partial sums ----------------
__global__ __launch_bounds__(256) void k_tpg(const float* __restrict__ xT,
                                             const float* __restrict__ wtT,
                                             const float* __restrict__ wpT,
                                             const float* __restrict__ wgT,
                                             float* __restrict__ tbuf,
                                             float* __restrict__ att) {
  __shared__ float xs[64][129];
  int b = blockIdx.y, s0 = blockIdx.x * 64, t = threadIdx.x;
  {
    int r = t >> 2, part = (t & 3) * 32;
    const float4* src = (const float4*)(xT + ((size_t)b * Sx + s0 + r) * 128 + part);
#pragma unroll
    for (int q = 0; q < 8; ++q) {
      float4 v = src[q];
      xs[r][part + q * 4 + 0] = v.x;
      xs[r][part + q * 4 + 1] = v.y;
      xs[r][part + q * 4 + 2] = v.z;
      xs[r][part + q * 4 + 3] = v.w;
    }
  }
  __syncthreads();
  int sg = t & 15, og = t >> 4;
  float ta[16], pa[16], ga[16];
#pragma unroll
  for (int k = 0; k < 16; ++k) { ta[k] = 0.f; pa[k] = 0.f; ga[k] = 0.f; }
  for (int c = 0; c < 128; ++c) {
    float xv[4];
#pragma unroll
    for (int j = 0; j < 4; ++j) xv[j] = xs[sg * 4 + j][c];
    float4 wtv = *(const float4*)(wtT + c * 64 + og * 4);
    float4 wpv = *(const float4*)(wpT + c * 64 + og * 4);
    float4 wgv = *(const float4*)(wgT + c * 64 + og * 4);
    float wa[4] = {wtv.x, wtv.y, wtv.z, wtv.w};
    float wb[4] = {wpv.x, wpv.y, wpv.z, wpv.w};
    float wc[4] = {wgv.x, wgv.y, wgv.z, wgv.w};
#pragma unroll
    for (int i = 0; i < 4; ++i)
#pragma unroll
      for (int j = 0; j < 4; ++j) {
        ta[i * 4 + j] = fmaf(wa[i], xv[j], ta[i * 4 + j]);
        pa[i * 4 + j] = fmaf(wb[i], xv[j], pa[i * 4 + j]);
        ga[i * 4 + j] = fmaf(wc[i], xv[j], ga[i * 4 + j]);
      }
  }
#pragma unroll
  for (int i = 0; i < 4; ++i)
#pragma unroll
    for (int j = 0; j < 4; ++j)
      tbuf[((size_t)b * 64 + og * 4 + i) * 256 + s0 + sg * 4 + j] = ta[i * 4 + j];
  float pv = 0.f;
#pragma unroll
  for (int k = 0; k < 16; ++k) pv += pa[k] * ga[k];
#pragma unroll
  for (int off = 32; off; off >>= 1) pv += __shfl_down(pv, off, 64);
  if ((t & 63) == 0) atomicAdd(att + b * 4 + (t >> 6), pv);  // wave w <=> group w
}

__device__ __forceinline__ float blocksum(float v, volatile float* red, int t) {
#pragma unroll
  for (int off = 32; off; off >>= 1) v += __shfl_down(v, off, 64);
  __syncthreads();
  if ((t & 63) == 0) red[t >> 6] = v;
  __syncthreads();
  return red[0] + red[1] + red[2] + red[3];
}

// ---------------- att*t, wz einsum, GroupNorm, residual ----------------
__global__ __launch_bounds__(256) void k_gn(const float* __restrict__ tbuf,
                                            const float* __restrict__ att,
                                            const float* __restrict__ wzF,
                                            const float* __restrict__ gngF,
                                            const float* __restrict__ gnbF,
                                            const float* __restrict__ xT,
                                            float* __restrict__ yT) {
  __shared__ float tg[16][256];
  __shared__ float wzs[32][16];
  __shared__ float red[4];
  int g = blockIdx.x, b = blockIdx.y, t = threadIdx.x;
  {
    int n = t >> 4, kk = (t & 15) * 16;
    const float4* src = (const float4*)(tbuf + ((size_t)b * 64 + g * 16 + n) * 256 + kk);
#pragma unroll
    for (int q = 0; q < 4; ++q) {
      float4 v = src[q];
      tg[n][kk + q * 4 + 0] = v.x;
      tg[n][kk + q * 4 + 1] = v.y;
      tg[n][kk + q * 4 + 2] = v.z;
      tg[n][kk + q * 4 + 3] = v.w;
    }
  }
  for (int i = t; i < 512; i += 256)
    wzs[i >> 4][i & 15] = wzF[(g * 32 + (i >> 4)) * 16 + (i & 15)];
  __syncthreads();
  float attv = att[b * 4 + g];
  int s = t;
  float yv[32];
#pragma unroll
  for (int o = 0; o < 32; ++o) yv[o] = 0.f;
  for (int c = 0; c < 16; ++c) {
    float tv = attv * tg[c][s];
#pragma unroll
    for (int o = 0; o < 32; ++o) yv[o] = fmaf(wzs[o][c], tv, yv[o]);
  }
  float ls = 0.f;
#pragma unroll
  for (int o = 0; o < 32; ++o) ls += yv[o];
  float mu = blocksum(ls, red, t) * (1.f / 8192.f);
  float lq = 0.f;
#pragma unroll
  for (int o = 0; o < 32; ++o) { float d = yv[o] - mu; lq = fmaf(d, d, lq); }
  float var = blocksum(lq, red, t) * (1.f / 8192.f);
  float rs = rsqrtf(var + 1e-5f);
  const float* xrow = xT + ((size_t)b * Sx + s) * 128 + g * 32;
  float* yrow = yT + ((size_t)b * Sx + s) * 128 + g * 32;
#pragma unroll
  for (int o = 0; o < 32; ++o) {
    int ch = g * 32 + o;
    yrow[o] = (yv[o] - mu) * rs * gngF[ch] + gnbF[ch] + xrow[o];
  }
}

// ---------------- FFN + box-head output assembly ----------------
__global__ __launch_bounds__(256) void k_ffn(const float* __restrict__ yT,
                                             const float* __restrict__ c1T, const float* __restrict__ d1,
                                             const float* __restrict__ c2T, const float* __restrict__ d2,
                                             const float* __restrict__ c3T, const float* __restrict__ c3bF,
                                             const float* __restrict__ nxyz,
                                             void* __restrict__ outp,
                                             const int* __restrict__ flagp) {
  __shared__ float ys[32][132];
  __shared__ float h1s[32][132];
  __shared__ float h2s[32][132];
  __shared__ float nets[32][44];
  int bf = *flagp;
  int b = blockIdx.y, s0 = blockIdx.x * 32, t = threadIdx.x;
  {
    int r = t >> 3, part = (t & 7) * 16;
    const float4* src = (const float4*)(yT + ((size_t)b * Sx + s0 + r) * 128 + part);
#pragma unroll
    for (int q = 0; q < 4; ++q) *(float4*)&ys[r][part + q * 4] = src[q];
  }
  __syncthreads();
  int o0 = (t & 31) * 4, sl0 = (t >> 5) * 4;
  float acc[16];
#pragma unroll
  for (int k = 0; k < 16; ++k) acc[k] = 0.f;
  for (int c = 0; c < 128; ++c) {
    float4 wv = *(const float4*)(c1T + c * 128 + o0);
    float yv[4];
#pragma unroll
    for (int j = 0; j < 4; ++j) yv[j] = ys[sl0 + j][c];
#pragma unroll
    for (int j = 0; j < 4; ++j) {
      acc[0 * 4 + j] = fmaf(wv.x, yv[j], acc[0 * 4 + j]);
      acc[1 * 4 + j] = fmaf(wv.y, yv[j], acc[1 * 4 + j]);
      acc[2 * 4 + j] = fmaf(wv.z, yv[j], acc[2 * 4 + j]);
      acc[3 * 4 + j] = fmaf(wv.w, yv[j], acc[3 * 4 + j]);
    }
  }
  {
    float4 dv = *(const float4*)(d1 + o0);
    float db[4] = {dv.x, dv.y, dv.z, dv.w};
#pragma unroll
    for (int i = 0; i < 4; ++i)
#pragma unroll
      for (int j = 0; j < 4; ++j)
        h1s[sl0 + j][o0 + i] = fmaxf(acc[i * 4 + j] + db[i], 0.f);
  }
  __syncthreads();
#pragma unroll
  for (int k = 0; k < 16; ++k) acc[k] = 0.f;
  for (int c = 0; c < 128; ++c) {
    float4 wv = *(const float4*)(c2T + c * 128 + o0);
    float yv[4];
#pragma unroll
    for (int j = 0; j < 4; ++j) yv[j] = h1s[sl0 + j][c];
#pragma unroll
    for (int j = 0; j < 4; ++j) {
      acc[0 * 4 + j] = fmaf(wv.x, yv[j], acc[0 * 4 + j]);
      acc[1 * 4 + j] = fmaf(wv.y, yv[j], acc[1 * 4 + j]);
      acc[2 * 4 + j] = fmaf(wv.z, yv[j], acc[2 * 4 + j]);
      acc[3 * 4 + j] = fmaf(wv.w, yv[j], acc[3 * 4 + j]);
    }
  }
  {
    float4 dv = *(const float4*)(d2 + o0);
    float db[4] = {dv.x, dv.y, dv.z, dv.w};
#pragma unroll
    for (int i = 0; i < 4; ++i)
#pragma unroll
      for (int j = 0; j < 4; ++j)
        h2s[sl0 + j][o0 + i] = fmaxf(acc[i * 4 + j] + db[i], 0.f);
  }
  __syncthreads();
  for (int f = t; f < 43 * 32; f += 256) {
    int o = f >> 5, s = f & 31;
    float a = c3bF[o];
    for (int c4 = 0; c4 < 32; ++c4) {
      float4 hv = *(const float4*)&h2s[s][c4 * 4];
      a = fmaf(hv.x, c3T[(c4 * 4 + 0) * 43 + o], a);
      a = fmaf(hv.y, c3T[(c4 * 4 + 1) * 43 + o], a);
      a = fmaf(hv.z, c3T[(c4 * 4 + 2) * 43 + o], a);
      a = fmaf(hv.w, c3T[(c4 * 4 + 3) * 43 + o], a);
    }
    nets[s][o] = a;
  }
  __syncthreads();
  const float PI12 = (float)(M_PI / 12.0);
  for (int f = t; f < 55 * 32; f += 256) {
    int s = f / 55, kk = f - s * 55;
    float v;
    if (kk < 5) {
      v = nets[s][kk];
      if (kk >= 2) v += nxyz[((size_t)b * Sx + s0 + s) * 3 + (kk - 2)];
    } else if (kk < 31) v = nets[s][kk];
    else if (kk < 43) v = nets[s][kk - 12] * PI12;
    else v = nets[s][kk - 12];
    size_t oi = ((size_t)b * Sx + s0 + s) * 55 + kk;
    if (bf) ((u16*)outp)[oi] = f2b(v);
    else    ((float*)outp)[oi] = v;
  }
}

extern "C" void kernel_launch(void* const* d_in, const int* in_sizes, int n_in,
                              void* d_out, int out_size, void* d_ws, size_t ws_size,
                              hipStream_t stream) {
  char* w = (char*)d_ws;
  u16*   featT = (u16*)(w + OFF_FEATT);
  float* xT    = (float*)(w + OFF_XT);
  float* tbuf  = (float*)(w + OFF_T);
  float* yT    = (float*)(w + OFF_YT);
  float* nxyz  = (float*)(w + OFF_NXYZ);
  int*   idxb  = (int*)(w + OFF_IDX);
  float* att   = (float*)(w + OFF_ATT);
  u16*   w0F   = (u16*)(w + OFF_W0F);
  float* b0    = (float*)(w + OFF_B0);
  u16*   w1F   = (u16*)(w + OFF_W1F);
  float* b1    = (float*)(w + OFF_B1);
  u16*   w2F   = (u16*)(w + OFF_W2F);
  float* b2    = (float*)(w + OFF_B2);
  float* wtT   = (float*)(w + OFF_WTT);
  float* wpT   = (float*)(w + OFF_WPT);
  float* wgT   = (float*)(w + OFF_WGT);
  float* c1T   = (float*)(w + OFF_C1T);
  float* d1    = (float*)(w + OFF_D1);
  float* c2T   = (float*)(w + OFF_C2T);
  float* d2    = (float*)(w + OFF_D2);
  float* c3T   = (float*)(w + OFF_C3T);
  float* xyzF  = (float*)(w + OFF_XYZF);
  float* wzF   = (float*)(w + OFF_WZF);
  float* gngF  = (float*)(w + OFF_GNG);
  float* gnbF  = (float*)(w + OFF_GNB);
  float* c3bF  = (float*)(w + OFF_C3B);
  int*   flag  = (int*)(w + OFF_FLAG);

  hipMemsetAsync(w + OFF_ATT, 0, 512, stream);
  k_sniff<<<1, 256, 0, stream>>>((const u32*)d_in[0], flag);
  k_cvt<<<(Bx * Nx * 3 + 255) / 256, 256, 0, stream>>>(d_in[0], xyzF, flag);
  k_prep<<<64, 256, 0, stream>>>(d_in[2], d_in[3], d_in[4], d_in[5], d_in[6], d_in[7], d_in[8],
                                 d_in[9], d_in[10], d_in[11], d_in[12], d_in[13], d_in[14],
                                 d_in[15], d_in[16], d_in[17], d_in[18], d_in[19], d_in[20],
                                 d_in[21], d_in[22], d_in[23], d_in[24], d_in[25], d_in[26],
                                 d_in[27], d_in[28],
                                 w0F, b0, w1F, b1, w2F, b2, wtT, wpT, wgT,
                                 c1T, d1, c2T, d2, c3T, wzF, gngF, gnbF, c3bF, flag);
  k_transpose<<<dim3(Nx / 32, CINx / 32, Bx), 256, 0, stream>>>(d_in[1], featT, flag);
  k_fps<<<Bx, 256, 0, stream>>>(xyzF, nxyz);
  k_ballq<<<(Bx * Sx) / 4, 256, 0, stream>>>(xyzF, nxyz, idxb);
  k_samlp<<<dim3(Sx / 4, Bx), 256, 0, stream>>>(featT, xyzF, nxyz, idxb,
                                                w0F, b0, w1F, b1, w2F, b2, xT);
  k_tpg<<<dim3(4, Bx), 256, 0, stream>>>(xT, wtT, wpT, wgT, tbuf, att);
  k_gn<<<dim3(4, Bx), 256, 0, stream>>>(tbuf, att, wzF, gngF, gnbF, xT, yT);
  k_ffn<<<dim3(8, Bx), 256, 0, stream>>>(yT, c1T, d1, c2T, d2, c3T, c3bF, nxyz,
                                         d_out, flag);
}

// Round 4
// 584.275 us; speedup vs baseline: 1.8612x; 1.1193x over previous
//
#include <hip/hip_runtime.h>
#include <hip/hip_bf16.h>
#include <math.h>

#define Bx   32
#define Nx   2048
#define Sx   256
#define NSx  16
#define CINx 256

typedef unsigned short u16;
typedef unsigned int   u32;
typedef short bf16x8 __attribute__((ext_vector_type(8)));
typedef float f32x4  __attribute__((ext_vector_type(4)));

__device__ __forceinline__ float b2f(u16 u) {
  union { u32 i; float f; } v; v.i = ((u32)u) << 16; return v.f;
}
__device__ __forceinline__ u16 f2b(float x) {  // RNE f32->bf16
  u32 u = __float_as_uint(x);
  u32 r = (u + 0x7FFFu + ((u >> 16) & 1u)) >> 16;
  return (u16)r;
}
// dtype-adaptive input load: bf=1 -> buffer holds bf16, bf=0 -> f32
__device__ __forceinline__ float ldin(const void* p, size_t i, int bf) {
  return bf ? b2f(((const u16*)p)[i]) : ((const float*)p)[i];
}

// ---------------- workspace layout (bytes) ----------------
#define OFF_FEATT 0                      // bf16 (B,N,C)   33554432
#define OFF_XT    (33554432)             // f32 (B,S,128)   4194304
#define OFF_T     (OFF_XT + 4194304)     // f32 (B,64,S)    2097152
#define OFF_YT    (OFF_T + 2097152)      // f32 (B,S,128)   4194304
#define OFF_NXYZ  (OFF_YT + 4194304)     // f32 (B,S,3)       98304
#define OFF_IDX   (OFF_NXYZ + 98304)     // i32 (B,S,16)     524288
#define OFF_ATT   (OFF_IDX + 524288)     // f32 (B,4)           512
#define OFF_W0F   (OFF_ATT + 512)        // bf16 frag-packed 9*8*64*8
#define OFF_B0    (OFF_W0F + 133120)
#define OFF_W1F   (OFF_B0 + 512)
#define OFF_B1    (OFF_W1F + 65536)
#define OFF_W2F   (OFF_B1 + 512)
#define OFF_B2    (OFF_W2F + 65536)
#define OFF_WTT   (OFF_B2 + 512)         // f32 128x64 (c-major)
#define OFF_WPT   (OFF_WTT + 32768)
#define OFF_WGT   (OFF_WPT + 32768)
#define OFF_C1T   (OFF_WGT + 32768)      // f32 128x128 (c-major, bn-folded)
#define OFF_D1    (OFF_C1T + 65536)
#define OFF_C2T   (OFF_D1 + 512)
#define OFF_D2    (OFF_C2T + 65536)
#define OFF_C3T   (OFF_D2 + 512)         // f32 128x43 (c-major)
#define OFF_WZF   (OFF_C3T + 22016)      // f32 128x16         8192
#define OFF_GNG   (OFF_WZF + 8192)       // f32 128             512
#define OFF_GNB   (OFF_GNG + 512)
#define OFF_C3B   (OFF_GNB + 512)        // f32 43              512
#define OFF_FLAG  (OFF_C3B + 512)        // i32                 512

// ---------------- dtype sniff: decide bf16 vs f32 inputs from xyz bits ----------------
__global__ __launch_bounds__(256) void k_sniff(const u32* __restrict__ w, int* __restrict__ flag) {
  __shared__ int cnt;
  int t = threadIdx.x;
  if (t == 0) cnt = 0;
  __syncthreads();
  u32 x = w[t];
  int e_lo = (x >> 7) & 0xFF;                 // exponent field if low u16 were a bf16
  if (e_lo >= 100 && e_lo <= 140) atomicAdd(&cnt, 1);
  __syncthreads();
  if (t == 0) *flag = (cnt > 128) ? 1 : 0;    // 1 = inputs are bf16
}

// ---------------- mega kernel: fps (blocks 0..31) + feature transpose (32..4127) + prep (4128..4191)
#define TRANS_BLKS 4096
__global__ __launch_bounds__(256) void k_mega(
    const void* __restrict__ xyzR, const void* __restrict__ featR,
    const void* sa_w0, const void* sa_w1, const void* sa_w2,
    const void* sa_g,  const void* sa_b,  const void* sa_m, const void* sa_v,
    const void* wt, const void* wp, const void* wg, const void* wzI,
    const void* gngI, const void* gnbI,
    const void* c1w, const void* c1b,
    const void* bn1g, const void* bn1b, const void* bn1m, const void* bn1v,
    const void* c2w, const void* c2b,
    const void* bn2g, const void* bn2b, const void* bn2m, const void* bn2v,
    const void* c3w, const void* c3bI,
    float* __restrict__ nxyz, u16* __restrict__ featT,
    u16* __restrict__ w0F, float* __restrict__ b0, u16* __restrict__ w1F, float* __restrict__ b1,
    u16* __restrict__ w2F, float* __restrict__ b2,
    float* __restrict__ wtT, float* __restrict__ wpT, float* __restrict__ wgT,
    float* __restrict__ c1T, float* __restrict__ d1, float* __restrict__ c2T, float* __restrict__ d2,
    float* __restrict__ c3T, float* __restrict__ wzF, float* __restrict__ gngF,
    float* __restrict__ gnbF, float* __restrict__ c3bF,
    const int* __restrict__ flagp) {
  __shared__ union {
    struct { float val[2][4]; int idx[2][4]; } fps;
    u16 tile[64][65];
  } sm;
  int bid = blockIdx.x, t = threadIdx.x;
  int bf = *flagp;

  if (bid < Bx) {
    // ---------------- FPS: 1 block per batch, contiguous 8 pts/thread ----------------
    int b = bid;
    const size_t xb = (size_t)b * Nx * 3;
    float px[8], py[8], pz[8], dist[8];
#pragma unroll
    for (int j = 0; j < 8; ++j) {
      int p = t * 8 + j;
      px[j] = ldin(xyzR, xb + p * 3 + 0, bf);
      py[j] = ldin(xyzR, xb + p * 3 + 1, bf);
      pz[j] = ldin(xyzR, xb + p * 3 + 2, bf);
      dist[j] = 1e10f;
    }
    int lane = t & 63, w = t >> 6;
    int far = 0, myind = 0;
    for (int it = 0; it < Sx; ++it) {
      if (t == it) myind = far;                 // scan emits pre-update far
      float cx = ldin(xyzR, xb + far * 3 + 0, bf);
      float cy = ldin(xyzR, xb + far * 3 + 1, bf);
      float cz = ldin(xyzR, xb + far * 3 + 2, bf);
      float bv = -1.f; int bj = 0;
#pragma unroll
      for (int j = 0; j < 8; ++j) {
        float dx = __fsub_rn(px[j], cx);
        float dy = __fsub_rn(py[j], cy);
        float dz = __fsub_rn(pz[j], cz);
        float d = __fadd_rn(__fadd_rn(__fmul_rn(dx, dx), __fmul_rn(dy, dy)), __fmul_rn(dz, dz));
        float nd = fminf(dist[j], d);
        dist[j] = nd;
        if (nd > bv) { bv = nd; bj = j; }       // j ascending => first index on tie
      }
      int bi = t * 8 + bj;
      // wave max (value-only butterfly); contiguous layout => first-index = lowest lane
      float wm = bv;
#pragma unroll
      for (int off = 1; off < 64; off <<= 1) wm = fmaxf(wm, __shfl_xor(wm, off, 64));
      unsigned long long mk = __ballot(bv == wm);
      int src = (int)__builtin_ctzll(mk);
      int wbi = __shfl(bi, src, 64);
      if (lane == 0) { sm.fps.val[it & 1][w] = wm; sm.fps.idx[it & 1][w] = wbi; }
      __syncthreads();
      // all threads redundantly reduce 4 wave results (no 2nd barrier; dbuf avoids WAR)
      float fv = sm.fps.val[it & 1][0]; int fi = sm.fps.idx[it & 1][0];
#pragma unroll
      for (int k2 = 1; k2 < 4; ++k2) {
        float v2 = sm.fps.val[it & 1][k2]; int i2 = sm.fps.idx[it & 1][k2];
        if (v2 > fv) { fv = v2; fi = i2; }      // ascending wave => first index on tie
      }
      far = fi;
    }
    float* o = nxyz + ((size_t)b * Sx + t) * 3;
    o[0] = ldin(xyzR, xb + myind * 3 + 0, bf);
    o[1] = ldin(xyzR, xb + myind * 3 + 1, bf);
    o[2] = ldin(xyzR, xb + myind * 3 + 2, bf);
  } else if (bid < Bx + TRANS_BLKS) {
    // ---------------- feature transpose (B,C,N)->(B,N,C) bf16, 64x64 tiles ----------------
    int tb = bid - Bx;
    int nblk = tb & 31, rest = tb >> 5;
    int cblk = rest & 3, b = rest >> 2;
    int n0 = nblk * 64, c0 = cblk * 64;
    int tx = t & 63, ty = t >> 6;
#pragma unroll
    for (int r = ty; r < 64; r += 4) {
      size_t src = ((size_t)(b * CINx + c0 + r)) * Nx + n0 + tx;
      sm.tile[r][tx] = bf ? ((const u16*)featR)[src] : f2b(((const float*)featR)[src]);
    }
    __syncthreads();
#pragma unroll
    for (int r = ty; r < 64; r += 4)
      featT[((size_t)(b * Nx + n0 + r)) * CINx + c0 + tx] = sm.tile[tx][r];
  } else {
    // ---------------- prep: fold BN, pack MFMA B-frags, transpose small weights ----------------
    int g0 = (bid - Bx - TRANS_BLKS) * 256 + t;
    const int gs = 64 * 256;
    for (int i = g0; i < 9 * 8 * 64 * 8; i += gs) {
      int j = i & 7, lane = (i >> 3) & 63, nt = (i >> 9) & 7, kt = i >> 12;
      int o = nt * 16 + (lane & 15);
      int c = kt * 32 + (lane >> 4) * 8 + j;
      float s = ldin(sa_g, o, bf) * rsqrtf(ldin(sa_v, o, bf) + 1e-5f);
      float w;
      if (c < 256) w = ldin(sa_w0, o * 259 + 3 + c, bf);
      else if (c < 259) w = ldin(sa_w0, o * 259 + (c - 256), bf);
      else w = 0.f;
      w0F[i] = f2b(w * s);
    }
    for (int i = g0; i < 4 * 8 * 64 * 8; i += gs) {
      int j = i & 7, lane = (i >> 3) & 63, nt = (i >> 9) & 7, kt = i >> 12;
      int o = nt * 16 + (lane & 15);
      int c = kt * 32 + (lane >> 4) * 8 + j;
      float s1 = ldin(sa_g, 128 + o, bf) * rsqrtf(ldin(sa_v, 128 + o, bf) + 1e-5f);
      float s2 = ldin(sa_g, 256 + o, bf) * rsqrtf(ldin(sa_v, 256 + o, bf) + 1e-5f);
      w1F[i] = f2b(ldin(sa_w1, o * 128 + c, bf) * s1);
      w2F[i] = f2b(ldin(sa_w2, o * 128 + c, bf) * s2);
    }
    for (int o = g0; o < 128; o += gs) {
      float s0 = ldin(sa_g, o, bf)       * rsqrtf(ldin(sa_v, o, bf)       + 1e-5f);
      float s1 = ldin(sa_g, 128 + o, bf) * rsqrtf(ldin(sa_v, 128 + o, bf) + 1e-5f);
      float s2 = ldin(sa_g, 256 + o, bf) * rsqrtf(ldin(sa_v, 256 + o, bf) + 1e-5f);
      b0[o] = ldin(sa_b, o, bf)       - ldin(sa_m, o, bf)       * s0;
      b1[o] = ldin(sa_b, 128 + o, bf) - ldin(sa_m, 128 + o, bf) * s1;
      b2[o] = ldin(sa_b, 256 + o, bf) - ldin(sa_m, 256 + o, bf) * s2;
      float sc1 = ldin(bn1g, o, bf) * rsqrtf(ldin(bn1v, o, bf) + 1e-5f);
      float sc2 = ldin(bn2g, o, bf) * rsqrtf(ldin(bn2v, o, bf) + 1e-5f);
      d1[o] = (ldin(c1b, o, bf) - ldin(bn1m, o, bf)) * sc1 + ldin(bn1b, o, bf);
      d2[o] = (ldin(c2b, o, bf) - ldin(bn2m, o, bf)) * sc2 + ldin(bn2b, o, bf);
      gngF[o] = ldin(gngI, o, bf);
      gnbF[o] = ldin(gnbI, o, bf);
    }
    for (int i = g0; i < 128 * 128; i += gs) {
      int o = i >> 7, c = i & 127;
      float sc1 = ldin(bn1g, o, bf) * rsqrtf(ldin(bn1v, o, bf) + 1e-5f);
      float sc2 = ldin(bn2g, o, bf) * rsqrtf(ldin(bn2v, o, bf) + 1e-5f);
      c1T[c * 128 + o] = ldin(c1w, i, bf) * sc1;
      c2T[c * 128 + o] = ldin(c2w, i, bf) * sc2;
    }
    for (int i = g0; i < 64 * 128; i += gs) {
      int o = i >> 7, c = i & 127;
      wtT[c * 64 + o] = ldin(wt, i, bf);
      wpT[c * 64 + o] = ldin(wp, i, bf);
      wgT[c * 64 + o] = ldin(wg, i, bf);
    }
    for (int i = g0; i < 43 * 128; i += gs) {
      int o = i >> 7, c = i & 127;
      c3T[c * 43 + o] = ldin(c3w, i, bf);
    }
    for (int i = g0; i < 2048; i += gs) wzF[i] = ldin(wzI, i, bf);
    for (int i = g0; i < 43; i += gs) c3bF[i] = ldin(c3bI, i, bf);
  }
}

// ---------------- ball query: 1 wave per (b,s), raw xyz ----------------
__global__ __launch_bounds__(256) void k_ballq(const void* __restrict__ xyzR,
                                               const float* __restrict__ nxyz,
                                               int* __restrict__ idxb,
                                               const int* __restrict__ flagp) {
  int bf = *flagp;
  int t = threadIdx.x;
  int wv = t >> 6, lane = t & 63;
  int gs = blockIdx.x * 4 + wv;           // b*S + s
  int b = gs >> 8;
  const size_t xb = (size_t)b * Nx * 3;
  const float* cen = nxyz + (size_t)gs * 3;
  float cx = cen[0], cy = cen[1], cz = cen[2];
  const float R2 = (float)(0.3 * 0.3);
  int* outp = idxb + (size_t)gs * NSx;
  int have = 0, first = 0;
  bool gotfirst = false;
  for (int ch = 0; ch < Nx / 64 && have < NSx; ++ch) {
    int p = ch * 64 + lane;
    float dx = __fsub_rn(ldin(xyzR, xb + p * 3 + 0, bf), cx);
    float dy = __fsub_rn(ldin(xyzR, xb + p * 3 + 1, bf), cy);
    float dz = __fsub_rn(ldin(xyzR, xb + p * 3 + 2, bf), cz);
    float d2 = __fadd_rn(__fadd_rn(__fmul_rn(dx, dx), __fmul_rn(dy, dy)), __fmul_rn(dz, dz));
    bool hit = d2 < R2;
    unsigned long long m = __ballot(hit);
    if (hit) {
      int pos = have + __popcll(m & ((1ull << lane) - 1ull));
      if (pos < NSx) outp[pos] = p;
    }
    if (!gotfirst && m) { first = ch * 64 + (int)__builtin_ctzll(m); gotfirst = true; }
    have += __popcll(m);
  }
  if (have < NSx && lane >= have && lane < NSx) outp[lane] = first;  // pad with first hit
}

// ---------------- SA-MLP via bf16 MFMA: 1 wave per (b,s) ----------------
// A-frag (M=16,K=32): lane holds A[m=lane&15][k=q*8+j]  (16 contiguous bytes)
// C/D: col=lane&15, row=q*4+reg
__global__ __launch_bounds__(256) void k_samlp(
    const u16* __restrict__ featT, const void* __restrict__ xyzR,
    const float* __restrict__ nxyz, const int* __restrict__ idxb,
    const u16* __restrict__ w0F, const float* __restrict__ b0v,
    const u16* __restrict__ w1F, const float* __restrict__ b1v,
    const u16* __restrict__ w2F, const float* __restrict__ b2v,
    float* __restrict__ xT, const int* __restrict__ flagp) {
  // per-wave LDS: ht[16][32] tail tile | hA[16][136] | hB[16][136]  (all bf16)
  __shared__ __align__(16) u16 lds[4][16 * 32 + 2 * 16 * 136];
  int bf = *flagp;
  int t = threadIdx.x, w = t >> 6, lane = t & 63;
  int s = blockIdx.x * 4 + w, b = blockIdx.y;
  u16* ht = &lds[w][0];
  u16* hA = &lds[w][512];
  u16* hB = &lds[w][512 + 2176];
  const int* gidx = idxb + ((size_t)b * Sx + s) * NSx;
  int m = lane & 15, q = lane >> 4;
  int pn = gidx[m];
  const float* cen = nxyz + ((size_t)b * Sx + s) * 3;
  // tail tile: cols 0..2 = rel-xyz, cols 3..31 = 0 (disjoint writes, no WAW)
  for (int i = lane; i < 16 * 32; i += 64)
    if ((i & 31) >= 3) ht[i] = 0;
  if (lane < 48) {
    int n2 = lane / 3, cc = lane - n2 * 3;
    int pn2 = gidx[n2];
    float v = (ldin(xyzR, ((size_t)b * Nx + pn2) * 3 + cc, bf) - cen[cc]) * (1.0f / 0.3f);
    ht[n2 * 32 + cc] = f2b(v);
  }
  __syncthreads();

  const bf16x8* wf0 = (const bf16x8*)w0F;
  const bf16x8* wf1 = (const bf16x8*)w1F;
  const bf16x8* wf2 = (const bf16x8*)w2F;
  f32x4 acc[8];

  // ---- layer 1: [16x288] x [288x128] ----
#pragma unroll
  for (int nt = 0; nt < 8; ++nt) acc[nt] = (f32x4){0.f, 0.f, 0.f, 0.f};
  const u16* arow = featT + ((size_t)b * Nx + pn) * CINx + q * 8;
#pragma unroll
  for (int kt = 0; kt < 9; ++kt) {
    bf16x8 a = (kt < 8) ? *(const bf16x8*)(arow + kt * 32)
                        : *(const bf16x8*)(ht + m * 32 + q * 8);
#pragma unroll
    for (int nt = 0; nt < 8; ++nt)
      acc[nt] = __builtin_amdgcn_mfma_f32_16x16x32_bf16(a, wf0[(kt * 8 + nt) * 64 + lane], acc[nt], 0, 0, 0);
  }
#pragma unroll
  for (int nt = 0; nt < 8; ++nt) {
    float bb = b0v[nt * 16 + m];
#pragma unroll
    for (int r = 0; r < 4; ++r)
      hA[(q * 4 + r) * 136 + nt * 16 + m] = f2b(fmaxf(acc[nt][r] + bb, 0.f));
  }
  __syncthreads();

  // ---- layer 2: [16x128] x [128x128] ----
#pragma unroll
  for (int nt = 0; nt < 8; ++nt) acc[nt] = (f32x4){0.f, 0.f, 0.f, 0.f};
#pragma unroll
  for (int kt = 0; kt < 4; ++kt) {
    bf16x8 a = *(const bf16x8*)(hA + m * 136 + kt * 32 + q * 8);
#pragma unroll
    for (int nt = 0; nt < 8; ++nt)
      acc[nt] = __builtin_amdgcn_mfma_f32_16x16x32_bf16(a, wf1[(kt * 8 + nt) * 64 + lane], acc[nt], 0, 0, 0);
  }
#pragma unroll
  for (int nt = 0; nt < 8; ++nt) {
    float bb = b1v[nt * 16 + m];
#pragma unroll
    for (int r = 0; r < 4; ++r)
      hB[(q * 4 + r) * 136 + nt * 16 + m] = f2b(fmaxf(acc[nt][r] + bb, 0.f));
  }
  __syncthreads();

  // ---- layer 3 + maxpool ----
#pragma unroll
  for (int nt = 0; nt < 8; ++nt) acc[nt] = (f32x4){0.f, 0.f, 0.f, 0.f};
#pragma unroll
  for (int kt = 0; kt < 4; ++kt) {
    bf16x8 a = *(const bf16x8*)(hB + m * 136 + kt * 32 + q * 8);
#pragma unroll
    for (int nt = 0; nt < 8; ++nt)
      acc[nt] = __builtin_amdgcn_mfma_f32_16x16x32_bf16(a, wf2[(kt * 8 + nt) * 64 + lane], acc[nt], 0, 0, 0);
  }
  float* xrow = xT + ((size_t)b * Sx + s) * 128;
#pragma unroll
  for (int nt = 0; nt < 8; ++nt) {
    float vm = fmaxf(fmaxf(acc[nt][0], acc[nt][1]), fmaxf(acc[nt][2], acc[nt][3]));
    vm = fmaxf(vm, __shfl_xor(vm, 16, 64));
    vm = fmaxf(vm, __shfl_xor(vm, 32, 64));   // max over all 16 neighbors
    float v = fmaxf(vm + b2v[nt * 16 + m], 0.f);  // relu(max+b) == max(relu(x+b))
    if (q == 0) xrow[nt * 16 + m] = v;
  }
}

// ---------------- t/p/g GEMMs + attention partial sums ----------------
__global__ __launch_bounds__(256) void k_tpg(const float* __restrict__ xT,
                                             const float* __restrict__ wtT,
                                             const float* __restrict__ wpT,
                                             const float* __restrict__ wgT,
                                             float* __restrict__ tbuf,
                                             float* __restrict__ att) {
  __shared__ float xs[64][129];
  int b = blockIdx.y, s0 = blockIdx.x * 64, t = threadIdx.x;
  {
    int r = t >> 2, part = (t & 3) * 32;
    const float4* src = (const float4*)(xT + ((size_t)b * Sx + s0 + r) * 128 + part);
#pragma unroll
    for (int q = 0; q < 8; ++q) {
      float4 v = src[q];
      xs[r][part + q * 4 + 0] = v.x;
      xs[r][part + q * 4 + 1] = v.y;
      xs[r][part + q * 4 + 2] = v.z;
      xs[r][part + q * 4 + 3] = v.w;
    }
  }
  __syncthreads();
  int sg = t & 15, og = t >> 4;
  float ta[16], pa[16], ga[16];
#pragma unroll
  for (int k = 0; k < 16; ++k) { ta[k] = 0.f; pa[k] = 0.f; ga[k] = 0.f; }
  for (int c = 0; c < 128; ++c) {
    float xv[4];
#pragma unroll
    for (int j = 0; j < 4; ++j) xv[j] = xs[sg * 4 + j][c];
    float4 wtv = *(const float4*)(wtT + c * 64 + og * 4);
    float4 wpv = *(const float4*)(wpT + c * 64 + og * 4);
    float4 wgv = *(const float4*)(wgT + c * 64 + og * 4);
    float wa[4] = {wtv.x, wtv.y, wtv.z, wtv.w};
    float wb[4] = {wpv.x, wpv.y, wpv.z, wpv.w};
    float wc[4] = {wgv.x, wgv.y, wgv.z, wgv.w};
#pragma unroll
    for (int i = 0; i < 4; ++i)
#pragma unroll
      for (int j = 0; j < 4; ++j) {
        ta[i * 4 + j] = fmaf(wa[i], xv[j], ta[i * 4 + j]);
        pa[i * 4 + j] = fmaf(wb[i], xv[j], pa[i * 4 + j]);
        ga[i * 4 + j] = fmaf(wc[i], xv[j], ga[i * 4 + j]);
      }
  }
#pragma unroll
  for (int i = 0; i < 4; ++i)
#pragma unroll
    for (int j = 0; j < 4; ++j)
      tbuf[((size_t)b * 64 + og * 4 + i) * 256 + s0 + sg * 4 + j] = ta[i * 4 + j];
  float pv = 0.f;
#pragma unroll
  for (int k = 0; k < 16; ++k) pv += pa[k] * ga[k];
#pragma unroll
  for (int off = 32; off; off >>= 1) pv += __shfl_down(pv, off, 64);
  if ((t & 63) == 0) atomicAdd(att + b * 4 + (t >> 6), pv);  // wave w <=> group w
}

__device__ __forceinline__ float blocksum(float v, volatile float* red, int t) {
#pragma unroll
  for (int off = 32; off; off >>= 1) v += __shfl_down(v, off, 64);
  __syncthreads();
  if ((t & 63) == 0) red[t >> 6] = v;
  __syncthreads();
  return red[0] + red[1] + red[2] + red[3];
}

// ---------------- att*t, wz einsum, GroupNorm, residual ----------------
__global__ __launch_bounds__(256) void k_gn(const float* __restrict__ tbuf,
                                            const float* __restrict__ att,
                                            const float* __restrict__ wzF,
                                            const float* __restrict__ gngF,
                                            const float* __restrict__ gnbF,
                                            const float* __restrict__ xT,
                                            float* __restrict__ yT) {
  __shared__ float tg[16][256];
  __shared__ float wzs[32][16];
  __shared__ float red[4];
  int g = blockIdx.x, b = blockIdx.y, t = threadIdx.x;
  {
    int n = t >> 4, kk = (t & 15) * 16;
    const float4* src = (const float4*)(tbuf + ((size_t)b * 64 + g * 16 + n) * 256 + kk);
#pragma unroll
    for (int q = 0; q < 4; ++q) {
      float4 v = src[q];
      tg[n][kk + q * 4 + 0] = v.x;
      tg[n][kk + q * 4 + 1] = v.y;
      tg[n][kk + q * 4 + 2] = v.z;
      tg[n][kk + q * 4 + 3] = v.w;
    }
  }
  for (int i = t; i < 512; i += 256)
    wzs[i >> 4][i & 15] = wzF[(g * 32 + (i >> 4)) * 16 + (i & 15)];
  __syncthreads();
  float attv = att[b * 4 + g];
  int s = t;
  float yv[32];
#pragma unroll
  for (int o = 0; o < 32; ++o) yv[o] = 0.f;
  for (int c = 0; c < 16; ++c) {
    float tv = attv * tg[c][s];
#pragma unroll
    for (int o = 0; o < 32; ++o) yv[o] = fmaf(wzs[o][c], tv, yv[o]);
  }
  float ls = 0.f;
#pragma unroll
  for (int o = 0; o < 32; ++o) ls += yv[o];
  float mu = blocksum(ls, red, t) * (1.f / 8192.f);
  float lq = 0.f;
#pragma unroll
  for (int o = 0; o < 32; ++o) { float d = yv[o] - mu; lq = fmaf(d, d, lq); }
  float var = blocksum(lq, red, t) * (1.f / 8192.f);
  float rs = rsqrtf(var + 1e-5f);
  const float* xrow = xT + ((size_t)b * Sx + s) * 128 + g * 32;
  float* yrow = yT + ((size_t)b * Sx + s) * 128 + g * 32;
#pragma unroll
  for (int o = 0; o < 32; ++o) {
    int ch = g * 32 + o;
    yrow[o] = (yv[o] - mu) * rs * gngF[ch] + gnbF[ch] + xrow[o];
  }
}

// ---------------- FFN + box-head output assembly ----------------
__global__ __launch_bounds__(256) void k_ffn(const float* __restrict__ yT,
                                             const float* __restrict__ c1T, const float* __restrict__ d1,
                                             const float* __restrict__ c2T, const float* __restrict__ d2,
                                             const float* __restrict__ c3T, const float* __restrict__ c3bF,
                                             const float* __restrict__ nxyz,
                                             void* __restrict__ outp,
                                             const int* __restrict__ flagp) {
  __shared__ float ys[32][132];
  __shared__ float h1s[32][132];
  __shared__ float h2s[32][132];
  __shared__ float nets[32][44];
  int bf = *flagp;
  int b = blockIdx.y, s0 = blockIdx.x * 32, t = threadIdx.x;
  {
    int r = t >> 3, part = (t & 7) * 16;
    const float4* src = (const float4*)(yT + ((size_t)b * Sx + s0 + r) * 128 + part);
#pragma unroll
    for (int q = 0; q < 4; ++q) *(float4*)&ys[r][part + q * 4] = src[q];
  }
  __syncthreads();
  int o0 = (t & 31) * 4, sl0 = (t >> 5) * 4;
  float acc[16];
#pragma unroll
  for (int k = 0; k < 16; ++k) acc[k] = 0.f;
  for (int c = 0; c < 128; ++c) {
    float4 wv = *(const float4*)(c1T + c * 128 + o0);
    float yv[4];
#pragma unroll
    for (int j = 0; j < 4; ++j) yv[j] = ys[sl0 + j][c];
#pragma unroll
    for (int j = 0; j < 4; ++j) {
      acc[0 * 4 + j] = fmaf(wv.x, yv[j], acc[0 * 4 + j]);
      acc[1 * 4 + j] = fmaf(wv.y, yv[j], acc[1 * 4 + j]);
      acc[2 * 4 + j] = fmaf(wv.z, yv[j], acc[2 * 4 + j]);
      acc[3 * 4 + j] = fmaf(wv.w, yv[j], acc[3 * 4 + j]);
    }
  }
  {
    float4 dv = *(const float4*)(d1 + o0);
    float db[4] = {dv.x, dv.y, dv.z, dv.w};
#pragma unroll
    for (int i = 0; i < 4; ++i)
#pragma unroll
      for (int j = 0; j < 4; ++j)
        h1s[sl0 + j][o0 + i] = fmaxf(acc[i * 4 + j] + db[i], 0.f);
  }
  __syncthreads();
#pragma unroll
  for (int k = 0; k < 16; ++k) acc[k] = 0.f;
  for (int c = 0; c < 128; ++c) {
    float4 wv = *(const float4*)(c2T + c * 128 + o0);
    float yv[4];
#pragma unroll
    for (int j = 0; j < 4; ++j) yv[j] = h1s[sl0 + j][c];
#pragma unroll
    for (int j = 0; j < 4; ++j) {
      acc[0 * 4 + j] = fmaf(wv.x, yv[j], acc[0 * 4 + j]);
      acc[1 * 4 + j] = fmaf(wv.y, yv[j], acc[1 * 4 + j]);
      acc[2 * 4 + j] = fmaf(wv.z, yv[j], acc[2 * 4 + j]);
      acc[3 * 4 + j] = fmaf(wv.w, yv[j], acc[3 * 4 + j]);
    }
  }
  {
    float4 dv = *(const float4*)(d2 + o0);
    float db[4] = {dv.x, dv.y, dv.z, dv.w};
#pragma unroll
    for (int i = 0; i < 4; ++i)
#pragma unroll
      for (int j = 0; j < 4; ++j)
        h2s[sl0 + j][o0 + i] = fmaxf(acc[i * 4 + j] + db[i], 0.f);
  }
  __syncthreads();
  for (int f = t; f < 43 * 32; f += 256) {
    int o = f >> 5, s = f & 31;
    float a = c3bF[o];
    for (int c4 = 0; c4 < 32; ++c4) {
      float4 hv = *(const float4*)&h2s[s][c4 * 4];
      a = fmaf(hv.x, c3T[(c4 * 4 + 0) * 43 + o], a);
      a = fmaf(hv.y, c3T[(c4 * 4 + 1) * 43 + o], a);
      a = fmaf(hv.z, c3T[(c4 * 4 + 2) * 43 + o], a);
      a = fmaf(hv.w, c3T[(c4 * 4 + 3) * 43 + o], a);
    }
    nets[s][o] = a;
  }
  __syncthreads();
  const float PI12 = (float)(M_PI / 12.0);
  for (int f = t; f < 55 * 32; f += 256) {
    int s = f / 55, kk = f - s * 55;
    float v;
    if (kk < 5) {
      v = nets[s][kk];
      if (kk >= 2) v += nxyz[((size_t)b * Sx + s0 + s) * 3 + (kk - 2)];
    } else if (kk < 31) v = nets[s][kk];
    else if (kk < 43) v = nets[s][kk - 12] * PI12;
    else v = nets[s][kk - 12];
    size_t oi = ((size_t)b * Sx + s0 + s) * 55 + kk;
    if (bf) ((u16*)outp)[oi] = f2b(v);
    else    ((float*)outp)[oi] = v;
  }
}

extern "C" void kernel_launch(void* const* d_in, const int* in_sizes, int n_in,
                              void* d_out, int out_size, void* d_ws, size_t ws_size,
                              hipStream_t stream) {
  char* w = (char*)d_ws;
  u16*   featT = (u16*)(w + OFF_FEATT);
  float* xT    = (float*)(w + OFF_XT);
  float* tbuf  = (float*)(w + OFF_T);
  float* yT    = (float*)(w + OFF_YT);
  float* nxyz  = (float*)(w + OFF_NXYZ);
  int*   idxb  = (int*)(w + OFF_IDX);
  float* att   = (float*)(w + OFF_ATT);
  u16*   w0F   = (u16*)(w + OFF_W0F);
  float* b0    = (float*)(w + OFF_B0);
  u16*   w1F   = (u16*)(w + OFF_W1F);
  float* b1    = (float*)(w + OFF_B1);
  u16*   w2F   = (u16*)(w + OFF_W2F);
  float* b2    = (float*)(w + OFF_B2);
  float* wtT   = (float*)(w + OFF_WTT);
  float* wpT   = (float*)(w + OFF_WPT);
  float* wgT   = (float*)(w + OFF_WGT);
  float* c1T   = (float*)(w + OFF_C1T);
  float* d1    = (float*)(w + OFF_D1);
  float* c2T   = (float*)(w + OFF_C2T);
  float* d2    = (float*)(w + OFF_D2);
  float* c3T   = (float*)(w + OFF_C3T);
  float* wzF   = (float*)(w + OFF_WZF);
  float* gngF  = (float*)(w + OFF_GNG);
  float* gnbF  = (float*)(w + OFF_GNB);
  float* c3bF  = (float*)(w + OFF_C3B);
  int*   flag  = (int*)(w + OFF_FLAG);

  hipMemsetAsync(w + OFF_ATT, 0, 512, stream);
  k_sniff<<<1, 256, 0, stream>>>((const u32*)d_in[0], flag);
  k_mega<<<Bx + TRANS_BLKS + 64, 256, 0, stream>>>(
      d_in[0], d_in[1],
      d_in[2], d_in[3], d_in[4], d_in[5], d_in[6], d_in[7], d_in[8],
      d_in[9], d_in[10], d_in[11], d_in[12], d_in[13], d_in[14],
      d_in[15], d_in[16], d_in[17], d_in[18], d_in[19], d_in[20],
      d_in[21], d_in[22], d_in[23], d_in[24], d_in[25], d_in[26],
      d_in[27], d_in[28],
      nxyz, featT,
      w0F, b0, w1F, b1, w2F, b2, wtT, wpT, wgT,
      c1T, d1, c2T, d2, c3T, wzF, gngF, gnbF, c3bF, flag);
  k_ballq<<<(Bx * Sx) / 4, 256, 0, stream>>>(d_in[0], nxyz, idxb, flag);
  k_samlp<<<dim3(Sx / 4, Bx), 256, 0, stream>>>(featT, d_in[0], nxyz, idxb,
                                                w0F, b0, w1F, b1, w2F, b2, xT, flag);
  k_tpg<<<dim3(4, Bx), 256, 0, stream>>>(xT, wtT, wpT, wgT, tbuf, att);
  k_gn<<<dim3(4, Bx), 256, 0, stream>>>(tbuf, att, wzF, gngF, gnbF, xT, yT);
  k_ffn<<<dim3(8, Bx), 256, 0, stream>>>(yT, c1T, d1, c2T, d2, c3T, c3bF, nxyz,
                                         d_out, flag);
}

// Round 5
// 473.619 us; speedup vs baseline: 2.2960x; 1.2336x over previous
//
#include <hip/hip_runtime.h>
#include <hip/hip_bf16.h>
#include <math.h>

#define Bx   32
#define Nx   2048
#define Sx   256
#define NSx  16
#define CINx 256

typedef unsigned short u16;
typedef unsigned int   u32;
typedef unsigned long long u64;
typedef short bf16x8 __attribute__((ext_vector_type(8)));
typedef float f32x4  __attribute__((ext_vector_type(4)));

__device__ __forceinline__ float b2f(u16 u) {
  union { u32 i; float f; } v; v.i = ((u32)u) << 16; return v.f;
}
__device__ __forceinline__ u16 f2b(float x) {  // RNE f32->bf16
  u32 u = __float_as_uint(x);
  u32 r = (u + 0x7FFFu + ((u >> 16) & 1u)) >> 16;
  return (u16)r;
}
// dtype-adaptive input load: bf=1 -> buffer holds bf16, bf=0 -> f32
__device__ __forceinline__ float ldin(const void* p, size_t i, int bf) {
  return bf ? b2f(((const u16*)p)[i]) : ((const float*)p)[i];
}

// DPP max-reduce step: x = max(x, lanes-shifted x); invalid source lanes keep x.
#define DPP_FMAX(x, ctrl)                                                      \
  x = fmaxf(x, __int_as_float(__builtin_amdgcn_update_dpp(                     \
          __float_as_int(x), __float_as_int(x), (ctrl), 0xf, 0xf, false)))

// ---------------- workspace layout (bytes) ----------------
#define OFF_FEATT 0                      // bf16 (B,N,C)   33554432
#define OFF_XT    (33554432)             // f32 (B,S,128)   4194304
#define OFF_T     (OFF_XT + 4194304)     // f32 (B,64,S)    2097152
#define OFF_YT    (OFF_T + 2097152)      // f32 (B,S,128)   4194304
#define OFF_NXYZ  (OFF_YT + 4194304)     // f32 (B,S,3)       98304
#define OFF_IDX   (OFF_NXYZ + 98304)     // i32 (B,S,16)     524288
#define OFF_ATT   (OFF_IDX + 524288)     // f32 (B,4)           512
#define OFF_W0F   (OFF_ATT + 512)        // bf16 frag-packed 9*8*64*8
#define OFF_B0    (OFF_W0F + 133120)
#define OFF_W1F   (OFF_B0 + 512)
#define OFF_B1    (OFF_W1F + 65536)
#define OFF_W2F   (OFF_B1 + 512)
#define OFF_B2    (OFF_W2F + 65536)
#define OFF_WTT   (OFF_B2 + 512)         // f32 128x64 (c-major)
#define OFF_WPT   (OFF_WTT + 32768)
#define OFF_WGT   (OFF_WPT + 32768)
#define OFF_C1T   (OFF_WGT + 32768)      // f32 128x128 (c-major, bn-folded)
#define OFF_D1    (OFF_C1T + 65536)
#define OFF_C2T   (OFF_D1 + 512)
#define OFF_D2    (OFF_C2T + 65536)
#define OFF_C3T   (OFF_D2 + 512)         // f32 128x43 (c-major)
#define OFF_WZF   (OFF_C3T + 22016)      // f32 128x16         8192
#define OFF_GNG   (OFF_WZF + 8192)       // f32 128             512
#define OFF_GNB   (OFF_GNG + 512)
#define OFF_C3B   (OFF_GNB + 512)        // f32 43              512
#define OFF_FLAG  (OFF_C3B + 512)        // i32                 512

// ---------------- dtype sniff: decide bf16 vs f32 inputs from xyz bits ----------------
__global__ __launch_bounds__(256) void k_sniff(const u32* __restrict__ w, int* __restrict__ flag) {
  __shared__ int cnt;
  int t = threadIdx.x;
  if (t == 0) cnt = 0;
  __syncthreads();
  u32 x = w[t];
  int e_lo = (x >> 7) & 0xFF;                 // exponent field if low u16 were a bf16
  if (e_lo >= 100 && e_lo <= 140) atomicAdd(&cnt, 1);
  __syncthreads();
  if (t == 0) *flag = (cnt > 128) ? 1 : 0;    // 1 = inputs are bf16
}

// ---------------- mega kernel: fps (blocks 0..31) + feature transpose (32..4127) + prep (4128..4191)
#define TRANS_BLKS 4096
__global__ __launch_bounds__(256) void k_mega(
    const void* __restrict__ xyzR, const void* __restrict__ featR,
    const void* sa_w0, const void* sa_w1, const void* sa_w2,
    const void* sa_g,  const void* sa_b,  const void* sa_m, const void* sa_v,
    const void* wt, const void* wp, const void* wg, const void* wzI,
    const void* gngI, const void* gnbI,
    const void* c1w, const void* c1b,
    const void* bn1g, const void* bn1b, const void* bn1m, const void* bn1v,
    const void* c2w, const void* c2b,
    const void* bn2g, const void* bn2b, const void* bn2m, const void* bn2v,
    const void* c3w, const void* c3bI,
    float* __restrict__ nxyz, u16* __restrict__ featT,
    u16* __restrict__ w0F, float* __restrict__ b0, u16* __restrict__ w1F, float* __restrict__ b1,
    u16* __restrict__ w2F, float* __restrict__ b2,
    float* __restrict__ wtT, float* __restrict__ wpT, float* __restrict__ wgT,
    float* __restrict__ c1T, float* __restrict__ d1, float* __restrict__ c2T, float* __restrict__ d2,
    float* __restrict__ c3T, float* __restrict__ wzF, float* __restrict__ gngF,
    float* __restrict__ gnbF, float* __restrict__ c3bF,
    const int* __restrict__ flagp) {
  __shared__ union {
    struct { float sxyz[Nx * 3]; u64 red[2][4]; } fps;   // 24640 B
    u16 tile[64][65];
  } sm;
  int bid = blockIdx.x, t = threadIdx.x;
  int bf = *flagp;

  if (bid < Bx) {
    // ---------------- FPS: 1 block per batch, xyz staged in LDS, DPP argmax ----------------
    int b = bid;
    const size_t xb = (size_t)b * Nx * 3;
    for (int i = t; i < Nx * 3; i += 256) sm.fps.sxyz[i] = ldin(xyzR, xb + i, bf);
    __syncthreads();
    float px[8], py[8], pz[8], dist[8];
#pragma unroll
    for (int j = 0; j < 8; ++j) {
      int p = t * 8 + j;
      px[j] = sm.fps.sxyz[p * 3 + 0];
      py[j] = sm.fps.sxyz[p * 3 + 1];
      pz[j] = sm.fps.sxyz[p * 3 + 2];
      dist[j] = 1e10f;
    }
    int lane = t & 63, w = t >> 6;
    int far = 0, myind = 0;
    for (int it = 0; it < Sx; ++it) {
      if (t == it) myind = far;                 // scan emits pre-update far
      float cx = sm.fps.sxyz[far * 3 + 0];
      float cy = sm.fps.sxyz[far * 3 + 1];
      float cz = sm.fps.sxyz[far * 3 + 2];
      float bv = -1.f; int bj = 0;
#pragma unroll
      for (int j = 0; j < 8; ++j) {
        float dx = __fsub_rn(px[j], cx);
        float dy = __fsub_rn(py[j], cy);
        float dz = __fsub_rn(pz[j], cz);
        float d = __fadd_rn(__fadd_rn(__fmul_rn(dx, dx), __fmul_rn(dy, dy)), __fmul_rn(dz, dz));
        float nd = fminf(dist[j], d);
        dist[j] = nd;
        if (nd > bv) { bv = nd; bj = j; }       // j ascending => first index on tie
      }
      int bi = t * 8 + bj;
      // wave max via DPP (VALU pipe); lane 63 ends with the wave max
      float x = bv;
      DPP_FMAX(x, 0x111);   // row_shr:1
      DPP_FMAX(x, 0x112);   // row_shr:2
      DPP_FMAX(x, 0x114);   // row_shr:4
      DPP_FMAX(x, 0x118);   // row_shr:8
      DPP_FMAX(x, 0x142);   // row_bcast:15
      DPP_FMAX(x, 0x143);   // row_bcast:31
      float wmax = __int_as_float(__builtin_amdgcn_readlane(__float_as_int(x), 63));
      u64 mk = __ballot(bv == wmax);
      int srcl = (int)__builtin_ctzll(mk);      // lowest lane = lowest point index
      int wbi = __builtin_amdgcn_readlane(bi, srcl);
      if (lane == 63)
        sm.fps.red[it & 1][w] = ((u64)__float_as_uint(wmax) << 32) | (u32)(~wbi);
      __syncthreads();
      // all threads redundantly reduce 4 packed keys (dist>=0 => uint order == float order)
      u64 k0 = sm.fps.red[it & 1][0], k1 = sm.fps.red[it & 1][1];
      u64 k2 = sm.fps.red[it & 1][2], k3 = sm.fps.red[it & 1][3];
      u64 best = k0 > k1 ? k0 : k1;
      if (k2 > best) best = k2;
      if (k3 > best) best = k3;
      far = (int)(u32)(~(u32)best);
    }
    float* o = nxyz + ((size_t)b * Sx + t) * 3;
    o[0] = sm.fps.sxyz[myind * 3 + 0];
    o[1] = sm.fps.sxyz[myind * 3 + 1];
    o[2] = sm.fps.sxyz[myind * 3 + 2];
  } else if (bid < Bx + TRANS_BLKS) {
    // ---------------- feature transpose (B,C,N)->(B,N,C) bf16, 64x64 tiles ----------------
    int tb = bid - Bx;
    int nblk = tb & 31, rest = tb >> 5;
    int cblk = rest & 3, b = rest >> 2;
    int n0 = nblk * 64, c0 = cblk * 64;
    int tx = t & 63, ty = t >> 6;
#pragma unroll
    for (int r = ty; r < 64; r += 4) {
      size_t src = ((size_t)(b * CINx + c0 + r)) * Nx + n0 + tx;
      sm.tile[r][tx] = bf ? ((const u16*)featR)[src] : f2b(((const float*)featR)[src]);
    }
    __syncthreads();
#pragma unroll
    for (int r = ty; r < 64; r += 4)
      featT[((size_t)(b * Nx + n0 + r)) * CINx + c0 + tx] = sm.tile[tx][r];
  } else {
    // ---------------- prep: fold BN, pack MFMA B-frags, transpose small weights ----------------
    int g0 = (bid - Bx - TRANS_BLKS) * 256 + t;
    const int gs = 64 * 256;
    for (int i = g0; i < 9 * 8 * 64 * 8; i += gs) {
      int j = i & 7, lane = (i >> 3) & 63, nt = (i >> 9) & 7, kt = i >> 12;
      int o = nt * 16 + (lane & 15);
      int c = kt * 32 + (lane >> 4) * 8 + j;
      float s = ldin(sa_g, o, bf) * rsqrtf(ldin(sa_v, o, bf) + 1e-5f);
      float w;
      if (c < 256) w = ldin(sa_w0, o * 259 + 3 + c, bf);
      else if (c < 259) w = ldin(sa_w0, o * 259 + (c - 256), bf);
      else w = 0.f;
      w0F[i] = f2b(w * s);
    }
    for (int i = g0; i < 4 * 8 * 64 * 8; i += gs) {
      int j = i & 7, lane = (i >> 3) & 63, nt = (i >> 9) & 7, kt = i >> 12;
      int o = nt * 16 + (lane & 15);
      int c = kt * 32 + (lane >> 4) * 8 + j;
      float s1 = ldin(sa_g, 128 + o, bf) * rsqrtf(ldin(sa_v, 128 + o, bf) + 1e-5f);
      float s2 = ldin(sa_g, 256 + o, bf) * rsqrtf(ldin(sa_v, 256 + o, bf) + 1e-5f);
      w1F[i] = f2b(ldin(sa_w1, o * 128 + c, bf) * s1);
      w2F[i] = f2b(ldin(sa_w2, o * 128 + c, bf) * s2);
    }
    for (int o = g0; o < 128; o += gs) {
      float s0 = ldin(sa_g, o, bf)       * rsqrtf(ldin(sa_v, o, bf)       + 1e-5f);
      float s1 = ldin(sa_g, 128 + o, bf) * rsqrtf(ldin(sa_v, 128 + o, bf) + 1e-5f);
      float s2 = ldin(sa_g, 256 + o, bf) * rsqrtf(ldin(sa_v, 256 + o, bf) + 1e-5f);
      b0[o] = ldin(sa_b, o, bf)       - ldin(sa_m, o, bf)       * s0;
      b1[o] = ldin(sa_b, 128 + o, bf) - ldin(sa_m, 128 + o, bf) * s1;
      b2[o] = ldin(sa_b, 256 + o, bf) - ldin(sa_m, 256 + o, bf) * s2;
      float sc1 = ldin(bn1g, o, bf) * rsqrtf(ldin(bn1v, o, bf) + 1e-5f);
      float sc2 = ldin(bn2g, o, bf) * rsqrtf(ldin(bn2v, o, bf) + 1e-5f);
      d1[o] = (ldin(c1b, o, bf) - ldin(bn1m, o, bf)) * sc1 + ldin(bn1b, o, bf);
      d2[o] = (ldin(c2b, o, bf) - ldin(bn2m, o, bf)) * sc2 + ldin(bn2b, o, bf);
      gngF[o] = ldin(gngI, o, bf);
      gnbF[o] = ldin(gnbI, o, bf);
    }
    for (int i = g0; i < 128 * 128; i += gs) {
      int o = i >> 7, c = i & 127;
      float sc1 = ldin(bn1g, o, bf) * rsqrtf(ldin(bn1v, o, bf) + 1e-5f);
      float sc2 = ldin(bn2g, o, bf) * rsqrtf(ldin(bn2v, o, bf) + 1e-5f);
      c1T[c * 128 + o] = ldin(c1w, i, bf) * sc1;
      c2T[c * 128 + o] = ldin(c2w, i, bf) * sc2;
    }
    for (int i = g0; i < 64 * 128; i += gs) {
      int o = i >> 7, c = i & 127;
      wtT[c * 64 + o] = ldin(wt, i, bf);
      wpT[c * 64 + o] = ldin(wp, i, bf);
      wgT[c * 64 + o] = ldin(wg, i, bf);
    }
    for (int i = g0; i < 43 * 128; i += gs) {
      int o = i >> 7, c = i & 127;
      c3T[c * 43 + o] = ldin(c3w, i, bf);
    }
    for (int i = g0; i < 2048; i += gs) wzF[i] = ldin(wzI, i, bf);
    for (int i = g0; i < 43; i += gs) c3bF[i] = ldin(c3bI, i, bf);
  }
}

// ---------------- ball query: 1 wave per (b,s), raw xyz ----------------
__global__ __launch_bounds__(256) void k_ballq(const void* __restrict__ xyzR,
                                               const float* __restrict__ nxyz,
                                               int* __restrict__ idxb,
                                               const int* __restrict__ flagp) {
  int bf = *flagp;
  int t = threadIdx.x;
  int wv = t >> 6, lane = t & 63;
  int gs = blockIdx.x * 4 + wv;           // b*S + s
  int b = gs >> 8;
  const size_t xb = (size_t)b * Nx * 3;
  const float* cen = nxyz + (size_t)gs * 3;
  float cx = cen[0], cy = cen[1], cz = cen[2];
  const float R2 = (float)(0.3 * 0.3);
  int* outp = idxb + (size_t)gs * NSx;
  int have = 0, first = 0;
  bool gotfirst = false;
  for (int ch = 0; ch < Nx / 64 && have < NSx; ++ch) {
    int p = ch * 64 + lane;
    float dx = __fsub_rn(ldin(xyzR, xb + p * 3 + 0, bf), cx);
    float dy = __fsub_rn(ldin(xyzR, xb + p * 3 + 1, bf), cy);
    float dz = __fsub_rn(ldin(xyzR, xb + p * 3 + 2, bf), cz);
    float d2 = __fadd_rn(__fadd_rn(__fmul_rn(dx, dx), __fmul_rn(dy, dy)), __fmul_rn(dz, dz));
    bool hit = d2 < R2;
    unsigned long long m = __ballot(hit);
    if (hit) {
      int pos = have + __popcll(m & ((1ull << lane) - 1ull));
      if (pos < NSx) outp[pos] = p;
    }
    if (!gotfirst && m) { first = ch * 64 + (int)__builtin_ctzll(m); gotfirst = true; }
    have += __popcll(m);
  }
  if (have < NSx && lane >= have && lane < NSx) outp[lane] = first;  // pad with first hit
}

// ---------------- SA-MLP via bf16 MFMA: 1 wave per (b,s) ----------------
// A-frag (M=16,K=32): lane holds A[m=lane&15][k=q*8+j]  (16 contiguous bytes)
// C/D: col=lane&15, row=q*4+reg
__global__ __launch_bounds__(256) void k_samlp(
    const u16* __restrict__ featT, const void* __restrict__ xyzR,
    const float* __restrict__ nxyz, const int* __restrict__ idxb,
    const u16* __restrict__ w0F, const float* __restrict__ b0v,
    const u16* __restrict__ w1F, const float* __restrict__ b1v,
    const u16* __restrict__ w2F, const float* __restrict__ b2v,
    float* __restrict__ xT, const int* __restrict__ flagp) {
  // per-wave LDS: ht[16][32] tail tile | hA[16][136] | hB[16][136]  (all bf16)
  __shared__ __align__(16) u16 lds[4][16 * 32 + 2 * 16 * 136];
  int bf = *flagp;
  int t = threadIdx.x, w = t >> 6, lane = t & 63;
  int s = blockIdx.x * 4 + w, b = blockIdx.y;
  u16* ht = &lds[w][0];
  u16* hA = &lds[w][512];
  u16* hB = &lds[w][512 + 2176];
  const int* gidx = idxb + ((size_t)b * Sx + s) * NSx;
  int m = lane & 15, q = lane >> 4;
  int pn = gidx[m];
  const float* cen = nxyz + ((size_t)b * Sx + s) * 3;
  // tail tile: cols 0..2 = rel-xyz, cols 3..31 = 0 (disjoint writes, no WAW)
  for (int i = lane; i < 16 * 32; i += 64)
    if ((i & 31) >= 3) ht[i] = 0;
  if (lane < 48) {
    int n2 = lane / 3, cc = lane - n2 * 3;
    int pn2 = gidx[n2];
    float v = (ldin(xyzR, ((size_t)b * Nx + pn2) * 3 + cc, bf) - cen[cc]) * (1.0f / 0.3f);
    ht[n2 * 32 + cc] = f2b(v);
  }
  __syncthreads();

  const bf16x8* wf0 = (const bf16x8*)w0F;
  const bf16x8* wf1 = (const bf16x8*)w1F;
  const bf16x8* wf2 = (const bf16x8*)w2F;
  f32x4 acc[8];

  // ---- layer 1: [16x288] x [288x128] ----
#pragma unroll
  for (int nt = 0; nt < 8; ++nt) acc[nt] = (f32x4){0.f, 0.f, 0.f, 0.f};
  const u16* arow = featT + ((size_t)b * Nx + pn) * CINx + q * 8;
#pragma unroll
  for (int kt = 0; kt < 9; ++kt) {
    bf16x8 a = (kt < 8) ? *(const bf16x8*)(arow + kt * 32)
                        : *(const bf16x8*)(ht + m * 32 + q * 8);
#pragma unroll
    for (int nt = 0; nt < 8; ++nt)
      acc[nt] = __builtin_amdgcn_mfma_f32_16x16x32_bf16(a, wf0[(kt * 8 + nt) * 64 + lane], acc[nt], 0, 0, 0);
  }
#pragma unroll
  for (int nt = 0; nt < 8; ++nt) {
    float bb = b0v[nt * 16 + m];
#pragma unroll
    for (int r = 0; r < 4; ++r)
      hA[(q * 4 + r) * 136 + nt * 16 + m] = f2b(fmaxf(acc[nt][r] + bb, 0.f));
  }
  __syncthreads();

  // ---- layer 2: [16x128] x [128x128] ----
#pragma unroll
  for (int nt = 0; nt < 8; ++nt) acc[nt] = (f32x4){0.f, 0.f, 0.f, 0.f};
#pragma unroll
  for (int kt = 0; kt < 4; ++kt) {
    bf16x8 a = *(const bf16x8*)(hA + m * 136 + kt * 32 + q * 8);
#pragma unroll
    for (int nt = 0; nt < 8; ++nt)
      acc[nt] = __builtin_amdgcn_mfma_f32_16x16x32_bf16(a, wf1[(kt * 8 + nt) * 64 + lane], acc[nt], 0, 0, 0);
  }
#pragma unroll
  for (int nt = 0; nt < 8; ++nt) {
    float bb = b1v[nt * 16 + m];
#pragma unroll
    for (int r = 0; r < 4; ++r)
      hB[(q * 4 + r) * 136 + nt * 16 + m] = f2b(fmaxf(acc[nt][r] + bb, 0.f));
  }
  __syncthreads();

  // ---- layer 3 + maxpool ----
#pragma unroll
  for (int nt = 0; nt < 8; ++nt) acc[nt] = (f32x4){0.f, 0.f, 0.f, 0.f};
#pragma unroll
  for (int kt = 0; kt < 4; ++kt) {
    bf16x8 a = *(const bf16x8*)(hB + m * 136 + kt * 32 + q * 8);
#pragma unroll
    for (int nt = 0; nt < 8; ++nt)
      acc[nt] = __builtin_amdgcn_mfma_f32_16x16x32_bf16(a, wf2[(kt * 8 + nt) * 64 + lane], acc[nt], 0, 0, 0);
  }
  float* xrow = xT + ((size_t)b * Sx + s) * 128;
#pragma unroll
  for (int nt = 0; nt < 8; ++nt) {
    float vm = fmaxf(fmaxf(acc[nt][0], acc[nt][1]), fmaxf(acc[nt][2], acc[nt][3]));
    vm = fmaxf(vm, __shfl_xor(vm, 16, 64));
    vm = fmaxf(vm, __shfl_xor(vm, 32, 64));   // max over all 16 neighbors
    float v = fmaxf(vm + b2v[nt * 16 + m], 0.f);  // relu(max+b) == max(relu(x+b))
    if (q == 0) xrow[nt * 16 + m] = v;
  }
}

// ---------------- t/p/g GEMMs + attention partial sums ----------------
__global__ __launch_bounds__(256) void k_tpg(const float* __restrict__ xT,
                                             const float* __restrict__ wtT,
                                             const float* __restrict__ wpT,
                                             const float* __restrict__ wgT,
                                             float* __restrict__ tbuf,
                                             float* __restrict__ att) {
  __shared__ float xs[64][129];
  int b = blockIdx.y, s0 = blockIdx.x * 64, t = threadIdx.x;
  {
    int r = t >> 2, part = (t & 3) * 32;
    const float4* src = (const float4*)(xT + ((size_t)b * Sx + s0 + r) * 128 + part);
#pragma unroll
    for (int q = 0; q < 8; ++q) {
      float4 v = src[q];
      xs[r][part + q * 4 + 0] = v.x;
      xs[r][part + q * 4 + 1] = v.y;
      xs[r][part + q * 4 + 2] = v.z;
      xs[r][part + q * 4 + 3] = v.w;
    }
  }
  __syncthreads();
  int sg = t & 15, og = t >> 4;
  float ta[16], pa[16], ga[16];
#pragma unroll
  for (int k = 0; k < 16; ++k) { ta[k] = 0.f; pa[k] = 0.f; ga[k] = 0.f; }
  for (int c = 0; c < 128; ++c) {
    float xv[4];
#pragma unroll
    for (int j = 0; j < 4; ++j) xv[j] = xs[sg * 4 + j][c];
    float4 wtv = *(const float4*)(wtT + c * 64 + og * 4);
    float4 wpv = *(const float4*)(wpT + c * 64 + og * 4);
    float4 wgv = *(const float4*)(wgT + c * 64 + og * 4);
    float wa[4] = {wtv.x, wtv.y, wtv.z, wtv.w};
    float wb[4] = {wpv.x, wpv.y, wpv.z, wpv.w};
    float wc[4] = {wgv.x, wgv.y, wgv.z, wgv.w};
#pragma unroll
    for (int i = 0; i < 4; ++i)
#pragma unroll
      for (int j = 0; j < 4; ++j) {
        ta[i * 4 + j] = fmaf(wa[i], xv[j], ta[i * 4 + j]);
        pa[i * 4 + j] = fmaf(wb[i], xv[j], pa[i * 4 + j]);
        ga[i * 4 + j] = fmaf(wc[i], xv[j], ga[i * 4 + j]);
      }
  }
#pragma unroll
  for (int i = 0; i < 4; ++i)
#pragma unroll
    for (int j = 0; j < 4; ++j)
      tbuf[((size_t)b * 64 + og * 4 + i) * 256 + s0 + sg * 4 + j] = ta[i * 4 + j];
  float pv = 0.f;
#pragma unroll
  for (int k = 0; k < 16; ++k) pv += pa[k] * ga[k];
#pragma unroll
  for (int off = 32; off; off >>= 1) pv += __shfl_down(pv, off, 64);
  if ((t & 63) == 0) atomicAdd(att + b * 4 + (t >> 6), pv);  // wave w <=> group w
}

__device__ __forceinline__ float blocksum(float v, volatile float* red, int t) {
#pragma unroll
  for (int off = 32; off; off >>= 1) v += __shfl_down(v, off, 64);
  __syncthreads();
  if ((t & 63) == 0) red[t >> 6] = v;
  __syncthreads();
  return red[0] + red[1] + red[2] + red[3];
}

// ---------------- att*t, wz einsum, GroupNorm, residual ----------------
__global__ __launch_bounds__(256) void k_gn(const float* __restrict__ tbuf,
                                            const float* __restrict__ att,
                                            const float* __restrict__ wzF,
                                            const float* __restrict__ gngF,
                                            const float* __restrict__ gnbF,
                                            const float* __restrict__ xT,
                                            float* __restrict__ yT) {
  __shared__ float tg[16][256];
  __shared__ float wzs[32][16];
  __shared__ float red[4];
  int g = blockIdx.x, b = blockIdx.y, t = threadIdx.x;
  {
    int n = t >> 4, kk = (t & 15) * 16;
    const float4* src = (const float4*)(tbuf + ((size_t)b * 64 + g * 16 + n) * 256 + kk);
#pragma unroll
    for (int q = 0; q < 4; ++q) {
      float4 v = src[q];
      tg[n][kk + q * 4 + 0] = v.x;
      tg[n][kk + q * 4 + 1] = v.y;
      tg[n][kk + q * 4 + 2] = v.z;
      tg[n][kk + q * 4 + 3] = v.w;
    }
  }
  for (int i = t; i < 512; i += 256)
    wzs[i >> 4][i & 15] = wzF[(g * 32 + (i >> 4)) * 16 + (i & 15)];
  __syncthreads();
  float attv = att[b * 4 + g];
  int s = t;
  float yv[32];
#pragma unroll
  for (int o = 0; o < 32; ++o) yv[o] = 0.f;
  for (int c = 0; c < 16; ++c) {
    float tv = attv * tg[c][s];
#pragma unroll
    for (int o = 0; o < 32; ++o) yv[o] = fmaf(wzs[o][c], tv, yv[o]);
  }
  float ls = 0.f;
#pragma unroll
  for (int o = 0; o < 32; ++o) ls += yv[o];
  float mu = blocksum(ls, red, t) * (1.f / 8192.f);
  float lq = 0.f;
#pragma unroll
  for (int o = 0; o < 32; ++o) { float d = yv[o] - mu; lq = fmaf(d, d, lq); }
  float var = blocksum(lq, red, t) * (1.f / 8192.f);
  float rs = rsqrtf(var + 1e-5f);
  const float* xrow = xT + ((size_t)b * Sx + s) * 128 + g * 32;
  float* yrow = yT + ((size_t)b * Sx + s) * 128 + g * 32;
#pragma unroll
  for (int o = 0; o < 32; ++o) {
    int ch = g * 32 + o;
    yrow[o] = (yv[o] - mu) * rs * gngF[ch] + gnbF[ch] + xrow[o];
  }
}

// ---------------- FFN + box-head output assembly ----------------
__global__ __launch_bounds__(256) void k_ffn(const float* __restrict__ yT,
                                             const float* __restrict__ c1T, const float* __restrict__ d1,
                                             const float* __restrict__ c2T, const float* __restrict__ d2,
                                             const float* __restrict__ c3T, const float* __restrict__ c3bF,
                                             const float* __restrict__ nxyz,
                                             void* __restrict__ outp,
                                             const int* __restrict__ flagp) {
  __shared__ float ys[32][132];
  __shared__ float h1s[32][132];
  __shared__ float h2s[32][132];
  __shared__ float nets[32][44];
  int bf = *flagp;
  int b = blockIdx.y, s0 = blockIdx.x * 32, t = threadIdx.x;
  {
    int r = t >> 3, part = (t & 7) * 16;
    const float4* src = (const float4*)(yT + ((size_t)b * Sx + s0 + r) * 128 + part);
#pragma unroll
    for (int q = 0; q < 4; ++q) *(float4*)&ys[r][part + q * 4] = src[q];
  }
  __syncthreads();
  int o0 = (t & 31) * 4, sl0 = (t >> 5) * 4;
  float acc[16];
#pragma unroll
  for (int k = 0; k < 16; ++k) acc[k] = 0.f;
  for (int c = 0; c < 128; ++c) {
    float4 wv = *(const float4*)(c1T + c * 128 + o0);
    float yv[4];
#pragma unroll
    for (int j = 0; j < 4; ++j) yv[j] = ys[sl0 + j][c];
#pragma unroll
    for (int j = 0; j < 4; ++j) {
      acc[0 * 4 + j] = fmaf(wv.x, yv[j], acc[0 * 4 + j]);
      acc[1 * 4 + j] = fmaf(wv.y, yv[j], acc[1 * 4 + j]);
      acc[2 * 4 + j] = fmaf(wv.z, yv[j], acc[2 * 4 + j]);
      acc[3 * 4 + j] = fmaf(wv.w, yv[j], acc[3 * 4 + j]);
    }
  }
  {
    float4 dv = *(const float4*)(d1 + o0);
    float db[4] = {dv.x, dv.y, dv.z, dv.w};
#pragma unroll
    for (int i = 0; i < 4; ++i)
#pragma unroll
      for (int j = 0; j < 4; ++j)
        h1s[sl0 + j][o0 + i] = fmaxf(acc[i * 4 + j] + db[i], 0.f);
  }
  __syncthreads();
#pragma unroll
  for (int k = 0; k < 16; ++k) acc[k] = 0.f;
  for (int c = 0; c < 128; ++c) {
    float4 wv = *(const float4*)(c2T + c * 128 + o0);
    float yv[4];
#pragma unroll
    for (int j = 0; j < 4; ++j) yv[j] = h1s[sl0 + j][c];
#pragma unroll
    for (int j = 0; j < 4; ++j) {
      acc[0 * 4 + j] = fmaf(wv.x, yv[j], acc[0 * 4 + j]);
      acc[1 * 4 + j] = fmaf(wv.y, yv[j], acc[1 * 4 + j]);
      acc[2 * 4 + j] = fmaf(wv.z, yv[j], acc[2 * 4 + j]);
      acc[3 * 4 + j] = fmaf(wv.w, yv[j], acc[3 * 4 + j]);
    }
  }
  {
    float4 dv = *(const float4*)(d2 + o0);
    float db[4] = {dv.x, dv.y, dv.z, dv.w};
#pragma unroll
    for (int i = 0; i < 4; ++i)
#pragma unroll
      for (int j = 0; j < 4; ++j)
        h2s[sl0 + j][o0 + i] = fmaxf(acc[i * 4 + j] + db[i], 0.f);
  }
  __syncthreads();
  for (int f = t; f < 43 * 32; f += 256) {
    int o = f >> 5, s = f & 31;
    float a = c3bF[o];
    for (int c4 = 0; c4 < 32; ++c4) {
      float4 hv = *(const float4*)&h2s[s][c4 * 4];
      a = fmaf(hv.x, c3T[(c4 * 4 + 0) * 43 + o], a);
      a = fmaf(hv.y, c3T[(c4 * 4 + 1) * 43 + o], a);
      a = fmaf(hv.z, c3T[(c4 * 4 + 2) * 43 + o], a);
      a = fmaf(hv.w, c3T[(c4 * 4 + 3) * 43 + o], a);
    }
    nets[s][o] = a;
  }
  __syncthreads();
  const float PI12 = (float)(M_PI / 12.0);
  for (int f = t; f < 55 * 32; f += 256) {
    int s = f / 55, kk = f - s * 55;
    float v;
    if (kk < 5) {
      v = nets[s][kk];
      if (kk >= 2) v += nxyz[((size_t)b * Sx + s0 + s) * 3 + (kk - 2)];
    } else if (kk < 31) v = nets[s][kk];
    else if (kk < 43) v = nets[s][kk - 12] * PI12;
    else v = nets[s][kk - 12];
    size_t oi = ((size_t)b * Sx + s0 + s) * 55 + kk;
    if (bf) ((u16*)outp)[oi] = f2b(v);
    else    ((float*)outp)[oi] = v;
  }
}

extern "C" void kernel_launch(void* const* d_in, const int* in_sizes, int n_in,
                              void* d_out, int out_size, void* d_ws, size_t ws_size,
                              hipStream_t stream) {
  char* w = (char*)d_ws;
  u16*   featT = (u16*)(w + OFF_FEATT);
  float* xT    = (float*)(w + OFF_XT);
  float* tbuf  = (float*)(w + OFF_T);
  float* yT    = (float*)(w + OFF_YT);
  float* nxyz  = (float*)(w + OFF_NXYZ);
  int*   idxb  = (int*)(w + OFF_IDX);
  float* att   = (float*)(w + OFF_ATT);
  u16*   w0F   = (u16*)(w + OFF_W0F);
  float* b0    = (float*)(w + OFF_B0);
  u16*   w1F   = (u16*)(w + OFF_W1F);
  float* b1    = (float*)(w + OFF_B1);
  u16*   w2F   = (u16*)(w + OFF_W2F);
  float* b2    = (float*)(w + OFF_B2);
  float* wtT   = (float*)(w + OFF_WTT);
  float* wpT   = (float*)(w + OFF_WPT);
  float* wgT   = (float*)(w + OFF_WGT);
  float* c1T   = (float*)(w + OFF_C1T);
  float* d1    = (float*)(w + OFF_D1);
  float* c2T   = (float*)(w + OFF_C2T);
  float* d2    = (float*)(w + OFF_D2);
  float* c3T   = (float*)(w + OFF_C3T);
  float* wzF   = (float*)(w + OFF_WZF);
  float* gngF  = (float*)(w + OFF_GNG);
  float* gnbF  = (float*)(w + OFF_GNB);
  float* c3bF  = (float*)(w + OFF_C3B);
  int*   flag  = (int*)(w + OFF_FLAG);

  hipMemsetAsync(w + OFF_ATT, 0, 512, stream);
  k_sniff<<<1, 256, 0, stream>>>((const u32*)d_in[0], flag);
  k_mega<<<Bx + TRANS_BLKS + 64, 256, 0, stream>>>(
      d_in[0], d_in[1],
      d_in[2], d_in[3], d_in[4], d_in[5], d_in[6], d_in[7], d_in[8],
      d_in[9], d_in[10], d_in[11], d_in[12], d_in[13], d_in[14],
      d_in[15], d_in[16], d_in[17], d_in[18], d_in[19], d_in[20],
      d_in[21], d_in[22], d_in[23], d_in[24], d_in[25], d_in[26],
      d_in[27], d_in[28],
      nxyz, featT,
      w0F, b0, w1F, b1, w2F, b2, wtT, wpT, wgT,
      c1T, d1, c2T, d2, c3T, wzF, gngF, gnbF, c3bF, flag);
  k_ballq<<<(Bx * Sx) / 4, 256, 0, stream>>>(d_in[0], nxyz, idxb, flag);
  k_samlp<<<dim3(Sx / 4, Bx), 256, 0, stream>>>(featT, d_in[0], nxyz, idxb,
                                                w0F, b0, w1F, b1, w2F, b2, xT, flag);
  k_tpg<<<dim3(4, Bx), 256, 0, stream>>>(xT, wtT, wpT, wgT, tbuf, att);
  k_gn<<<dim3(4, Bx), 256, 0, stream>>>(tbuf, att, wzF, gngF, gnbF, xT, yT);
  k_ffn<<<dim3(8, Bx), 256, 0, stream>>>(yT, c1T, d1, c2T, d2, c3T, c3bF, nxyz,
                                         d_out, flag);
}